// Round 1
// baseline (5147.494 us; speedup 1.0000x reference)
//
#include <hip/hip_runtime.h>
#include <math.h>

#define DIMC 384
#define NHEADS 8
#define CHD 48
#define HWN 16384
#define IMW 128
#define PERT ((size_t)DIMC * HWN)   // 6,291,456 floats per [384,128,128] tensor

// ---------------------------------------------------------------------------
// GEMM body: Y[otile*64 .. +64, ntile*256 .. +256] = W[384x384] * X[384x16384]
// BM=64, BN=256, BK=16, 256 threads, 8x8 outputs per thread. fp32.
// ---------------------------------------------------------------------------
__device__ __forceinline__ void gemm384_body(
    const float* __restrict__ W, const float* __restrict__ X,
    float* __restrict__ Y, int otile, int ntile)
{
  __shared__ float Ws[16][64];    // [k][o], transposed for broadcast reads
  __shared__ float Xs[16][256];   // [k][n]
  const int tid = threadIdx.x;
  const int tx = tid & 31;        // n-group: n = tx*8 .. +7
  const int ty = tid >> 5;        // o-group: o = ty*8 .. +7
  const int obase = otile * 64;
  const int nbase = ntile * 256;

  float acc[8][8];
#pragma unroll
  for (int i = 0; i < 8; ++i)
#pragma unroll
    for (int j = 0; j < 8; ++j) acc[i][j] = 0.f;

  const int wo = tid >> 2;         // 0..63
  const int wk = (tid & 3) << 2;   // 0,4,8,12

  for (int k0 = 0; k0 < DIMC; k0 += 16) {
    // global loads first (let them overlap), then LDS writes
    float4 wv = *reinterpret_cast<const float4*>(&W[(size_t)(obase + wo) * DIMC + k0 + wk]);
    float4 xv[4];
#pragma unroll
    for (int i = 0; i < 4; ++i) {
      int l = tid + i * 256;        // 0..1023 over 16x256/4 float4 slots
      int r = l >> 6, c4 = l & 63;
      xv[i] = *reinterpret_cast<const float4*>(&X[(size_t)(k0 + r) * HWN + nbase + c4 * 4]);
    }
#pragma unroll
    for (int i = 0; i < 4; ++i) {
      int l = tid + i * 256;
      int r = l >> 6, c4 = l & 63;
      *reinterpret_cast<float4*>(&Xs[r][c4 * 4]) = xv[i];
    }
    Ws[wk + 0][wo] = wv.x;
    Ws[wk + 1][wo] = wv.y;
    Ws[wk + 2][wo] = wv.z;
    Ws[wk + 3][wo] = wv.w;
    __syncthreads();
#pragma unroll
    for (int kk = 0; kk < 16; ++kk) {
      float4 b0 = *reinterpret_cast<const float4*>(&Xs[kk][tx * 8]);
      float4 b1 = *reinterpret_cast<const float4*>(&Xs[kk][tx * 8 + 4]);
      float a[8];
#pragma unroll
      for (int i = 0; i < 8; ++i) a[i] = Ws[kk][ty * 8 + i];
      const float b[8] = {b0.x, b0.y, b0.z, b0.w, b1.x, b1.y, b1.z, b1.w};
#pragma unroll
      for (int i = 0; i < 8; ++i)
#pragma unroll
        for (int j = 0; j < 8; ++j)
          acc[i][j] = fmaf(a[i], b[j], acc[i][j]);
    }
    __syncthreads();
  }
#pragma unroll
  for (int i = 0; i < 8; ++i) {
    float* yrow = &Y[(size_t)(obase + ty * 8 + i) * HWN + nbase + tx * 8];
    *reinterpret_cast<float4*>(yrow)     = make_float4(acc[i][0], acc[i][1], acc[i][2], acc[i][3]);
    *reinterpret_cast<float4*>(yrow + 4) = make_float4(acc[i][4], acc[i][5], acc[i][6], acc[i][7]);
  }
}

// conv1x1 for q0,k0,v0 in one launch. grid = (18, 64): 18 = 3 tensors x 6 o-tiles.
// XCD-swizzled so each XCD owns a contiguous range of n-tiles (x-tile L2 reuse).
__global__ __launch_bounds__(256) void k_conv1x1_qkv(
    const float* __restrict__ x, const float* __restrict__ w0,
    const float* __restrict__ w1, const float* __restrict__ w2,
    float* __restrict__ y)
{
  int lin = blockIdx.y * 18 + blockIdx.x;        // 0..1151
  int swz = (lin & 7) * 144 + (lin >> 3);        // 1152/8 = 144 per XCD
  int ntile = swz / 18;
  int r = swz - ntile * 18;
  int j = r / 6, otile = r - j * 6;
  const float* W = (j == 0) ? w0 : (j == 1) ? w1 : w2;
  gemm384_body(W, x, y + (size_t)j * PERT, otile, ntile);
}

// final: out_b = M_b @ v. grid = (6, 64)
__global__ __launch_bounds__(256) void k_gemm_final(
    const float* __restrict__ M, const float* __restrict__ v,
    float* __restrict__ out)
{
  int lin = blockIdx.y * 6 + blockIdx.x;         // 0..383
  int swz = (lin & 7) * 48 + (lin >> 3);
  int ntile = swz / 6, otile = swz - ntile * 6;
  gemm384_body(M, v, out, otile, ntile);
}

// depthwise 3x3 SAME (cross-correlation, matching XLA/torch), one thread per
// output element; fused sum-of-squares accumulation for q (j=0) and k (j=1).
__global__ __launch_bounds__(256) void k_dwconv(
    const float* __restrict__ Yin, const float* __restrict__ dw0,
    const float* __restrict__ dw1, const float* __restrict__ dw2,
    float* __restrict__ Zout, float* __restrict__ sumsq)
{
  int idx = blockIdx.x * 256 + threadIdx.x;      // over 3*384*16384
  int j = idx / (DIMC * HWN);
  int rem = idx - j * (DIMC * HWN);
  int c = rem >> 14;
  int n = rem & (HWN - 1);
  int h = n >> 7, w = n & (IMW - 1);
  const float* dw = ((j == 0) ? dw0 : (j == 1) ? dw1 : dw2) + c * 9;
  const float* src = Yin + (size_t)(j * DIMC + c) * HWN;
  float a = 0.f;
#pragma unroll
  for (int dy = -1; dy <= 1; ++dy) {
    int hh = h + dy;
    if (hh < 0 || hh >= IMW) continue;
#pragma unroll
    for (int dx = -1; dx <= 1; ++dx) {
      int ww = w + dx;
      if (ww < 0 || ww >= IMW) continue;
      a = fmaf(src[hh * IMW + ww], dw[(dy + 1) * 3 + (dx + 1)], a);
    }
  }
  Zout[idx] = a;
  if (j < 2) {
    float s = a * a;                              // wave = 64 lanes, same c
#pragma unroll
    for (int off = 32; off > 0; off >>= 1) s += __shfl_down(s, off);
    if ((threadIdx.x & 63) == 0) atomicAdd(&sumsq[j * DIMC + c], s);
  }
}

// Sraw[h][c][d] += sum_n q[h*48+c][n] * k[h*48+d][n]
// grid = 256 blocks (8 heads x 32 slices of 512 px), 256 threads,
// 3x3 (c,d) pairs per thread over LDS-transposed tiles.
__global__ __launch_bounds__(256) void k_qkdot(
    const float* __restrict__ q, const float* __restrict__ k,
    float* __restrict__ Sraw)
{
  int h = blockIdx.x & 7;
  int slice = blockIdx.x >> 3;
  int n0 = slice * 512;
  __shared__ float qs[64][49];   // [pixel][c], padded
  __shared__ float ks[64][49];
  int tid = threadIdx.x;
  int tc = tid >> 4, td = tid & 15;
  float acc[3][3];
#pragma unroll
  for (int i = 0; i < 3; ++i)
#pragma unroll
    for (int jj = 0; jj < 3; ++jj) acc[i][jj] = 0.f;

  const float* qb = q + (size_t)h * CHD * HWN;
  const float* kb = k + (size_t)h * CHD * HWN;
  for (int nn = n0; nn < n0 + 512; nn += 64) {
#pragma unroll
    for (int i = 0; i < 12; ++i) {               // 48*64/256 = 12 each
      int l = tid + i * 256;
      int c = l >> 6, p = l & 63;
      qs[p][c] = qb[(size_t)c * HWN + nn + p];
      ks[p][c] = kb[(size_t)c * HWN + nn + p];
    }
    __syncthreads();
#pragma unroll 8
    for (int p = 0; p < 64; ++p) {
      float qv[3], kv[3];
#pragma unroll
      for (int i = 0; i < 3; ++i) qv[i] = qs[p][tc * 3 + i];
#pragma unroll
      for (int i = 0; i < 3; ++i) kv[i] = ks[p][td * 3 + i];
#pragma unroll
      for (int i = 0; i < 3; ++i)
#pragma unroll
        for (int jj = 0; jj < 3; ++jj)
          acc[i][jj] = fmaf(qv[i], kv[jj], acc[i][jj]);
    }
    __syncthreads();
  }
#pragma unroll
  for (int i = 0; i < 3; ++i)
#pragma unroll
    for (int jj = 0; jj < 3; ++jj)
      atomicAdd(&Sraw[(h * CHD + tc * 3 + i) * CHD + td * 3 + jj], acc[i][jj]);
}

// softmax over d with fused L2-norm scaling: one block of 384 threads,
// thread t = row (h*48+c).
__global__ __launch_bounds__(384) void k_softmax(
    const float* __restrict__ S, const float* __restrict__ sumsq,
    const float* __restrict__ temp, float* __restrict__ A)
{
  __shared__ float sk[DIMC];
  int t = threadIdx.x;
  sk[t] = 1.f / fmaxf(sqrtf(sumsq[DIMC + t]), 1e-12f);   // k-row scales
  float invq = 1.f / fmaxf(sqrtf(sumsq[t]), 1e-12f);
  __syncthreads();
  int h = t / CHD;
  float tp = temp[h];
  const float* Srow = S + t * CHD;
  float vals[CHD];
  float mx = -1e30f;
#pragma unroll
  for (int d = 0; d < CHD; ++d) {
    float v = Srow[d] * invq * sk[h * CHD + d] * tp;
    vals[d] = v;
    mx = fmaxf(mx, v);
  }
  float sum = 0.f;
#pragma unroll
  for (int d = 0; d < CHD; ++d) { vals[d] = expf(vals[d] - mx); sum += vals[d]; }
  float inv = 1.f / sum;
  float* Arow = A + t * CHD;
#pragma unroll
  for (int d = 0; d < CHD; ++d) Arow[d] = vals[d] * inv;
}

// M[o][dg] = sum_{c'} wproj[o][h(dg)*48+c'] * A[h(dg)][c'][d'(dg)]
// Folds attn@v + proj conv into one 384x384 matrix per batch.
__global__ __launch_bounds__(256) void k_combine(
    const float* __restrict__ wproj, const float* __restrict__ A,
    float* __restrict__ M)
{
  int idx = blockIdx.x * 256 + threadIdx.x;      // over 384*384
  int o = idx / DIMC;
  int dg = idx - o * DIMC;
  int h = dg / CHD, d = dg - h * CHD;
  const float* wrow = wproj + (size_t)o * DIMC + h * CHD;
  const float* Acol = A + (size_t)(h * CHD) * CHD + d;
  float s = 0.f;
#pragma unroll
  for (int c = 0; c < CHD; ++c)
    s = fmaf(wrow[c], Acol[c * CHD], s);
  M[idx] = s;
}

extern "C" void kernel_launch(void* const* d_in, const int* in_sizes, int n_in,
                              void* d_out, int out_size, void* d_ws, size_t ws_size,
                              hipStream_t stream)
{
  const float* x     = (const float*)d_in[0];
  const float* w0    = (const float*)d_in[1];
  const float* w1    = (const float*)d_in[2];
  const float* w2    = (const float*)d_in[3];
  const float* dw0   = (const float*)d_in[4];
  const float* dw1   = (const float*)d_in[5];
  const float* dw2   = (const float*)d_in[6];
  const float* wproj = (const float*)d_in[7];
  const float* temp  = (const float*)d_in[8];
  float* out = (float*)d_out;

  // ws layout (per-batch reuse): ~145 MB
  float* qkv0  = (float*)d_ws;                       // 3*PERT
  float* qkv   = qkv0 + 3 * PERT;                    // 3*PERT (q,k,v)
  float* Sraw  = qkv + 3 * PERT;                     // 8*48*48
  float* sumsq = Sraw + NHEADS * CHD * CHD;          // 2*384
  float* Aat   = sumsq + 2 * DIMC;                   // 8*48*48
  float* Mm    = Aat + NHEADS * CHD * CHD;           // 384*384

  for (int b = 0; b < 8; ++b) {
    const float* xb = x + (size_t)b * PERT;
    float* outb = out + (size_t)b * PERT;
    hipMemsetAsync(Sraw, 0, (NHEADS * CHD * CHD + 2 * DIMC) * sizeof(float), stream);
    k_conv1x1_qkv<<<dim3(18, 64), 256, 0, stream>>>(xb, w0, w1, w2, qkv0);
    k_dwconv<<<(3 * DIMC * HWN) / 256, 256, 0, stream>>>(qkv0, dw0, dw1, dw2, qkv, sumsq);
    k_qkdot<<<256, 256, 0, stream>>>(qkv, qkv + PERT, Sraw);
    k_softmax<<<1, DIMC, 0, stream>>>(Sraw, sumsq, temp, Aat);
    k_combine<<<(DIMC * DIMC) / 256, 256, 0, stream>>>(wproj, Aat, Mm);
    k_gemm_final<<<dim3(6, 64), 256, 0, stream>>>(Mm, qkv + 2 * PERT, outb);
  }
  (void)in_sizes; (void)n_in; (void)out_size; (void)ws_size;
}

// Round 2
// 3318.567 us; speedup vs baseline: 1.5511x; 1.5511x over previous
//
#include <hip/hip_runtime.h>
#include <math.h>

#define DIMC 384
#define NHEADS 8
#define CHD 48
#define HWN 16384
#define IMW 128
#define PERT ((size_t)DIMC * HWN)   // 6,291,456 floats per [384,128,128] tensor
#define NPLANES (3 * DIMC)          // 1152 planes in qkv0
#define BLKS_PER_PLANE 64           // 16384 px / 256 threads

// ---------------------------------------------------------------------------
// GEMM body: Y[otile*64 .. +64, ntile*256 .. +256] = W[384x384] * X[384x16384]
// BM=64, BN=256, BK=16, 256 threads, 8x8 outputs per thread. fp32.
// ---------------------------------------------------------------------------
__device__ __forceinline__ void gemm384_body(
    const float* __restrict__ W, const float* __restrict__ X,
    float* __restrict__ Y, int otile, int ntile)
{
  __shared__ float Ws[16][64];    // [k][o], transposed for broadcast reads
  __shared__ float Xs[16][256];   // [k][n]
  const int tid = threadIdx.x;
  const int tx = tid & 31;        // n-group: n = tx*8 .. +7
  const int ty = tid >> 5;        // o-group: o = ty*8 .. +7
  const int obase = otile * 64;
  const int nbase = ntile * 256;

  float acc[8][8];
#pragma unroll
  for (int i = 0; i < 8; ++i)
#pragma unroll
    for (int j = 0; j < 8; ++j) acc[i][j] = 0.f;

  const int wo = tid >> 2;         // 0..63
  const int wk = (tid & 3) << 2;   // 0,4,8,12

  for (int k0 = 0; k0 < DIMC; k0 += 16) {
    float4 wv = *reinterpret_cast<const float4*>(&W[(size_t)(obase + wo) * DIMC + k0 + wk]);
    float4 xv[4];
#pragma unroll
    for (int i = 0; i < 4; ++i) {
      int l = tid + i * 256;
      int r = l >> 6, c4 = l & 63;
      xv[i] = *reinterpret_cast<const float4*>(&X[(size_t)(k0 + r) * HWN + nbase + c4 * 4]);
    }
#pragma unroll
    for (int i = 0; i < 4; ++i) {
      int l = tid + i * 256;
      int r = l >> 6, c4 = l & 63;
      *reinterpret_cast<float4*>(&Xs[r][c4 * 4]) = xv[i];
    }
    Ws[wk + 0][wo] = wv.x;
    Ws[wk + 1][wo] = wv.y;
    Ws[wk + 2][wo] = wv.z;
    Ws[wk + 3][wo] = wv.w;
    __syncthreads();
#pragma unroll
    for (int kk = 0; kk < 16; ++kk) {
      float4 b0 = *reinterpret_cast<const float4*>(&Xs[kk][tx * 8]);
      float4 b1 = *reinterpret_cast<const float4*>(&Xs[kk][tx * 8 + 4]);
      float a[8];
#pragma unroll
      for (int i = 0; i < 8; ++i) a[i] = Ws[kk][ty * 8 + i];
      const float b[8] = {b0.x, b0.y, b0.z, b0.w, b1.x, b1.y, b1.z, b1.w};
#pragma unroll
      for (int i = 0; i < 8; ++i)
#pragma unroll
        for (int j = 0; j < 8; ++j)
          acc[i][j] = fmaf(a[i], b[j], acc[i][j]);
    }
    __syncthreads();
  }
#pragma unroll
  for (int i = 0; i < 8; ++i) {
    float* yrow = &Y[(size_t)(obase + ty * 8 + i) * HWN + nbase + tx * 8];
    *reinterpret_cast<float4*>(yrow)     = make_float4(acc[i][0], acc[i][1], acc[i][2], acc[i][3]);
    *reinterpret_cast<float4*>(yrow + 4) = make_float4(acc[i][4], acc[i][5], acc[i][6], acc[i][7]);
  }
}

// conv1x1 for q0,k0,v0 in one launch. grid = (18, 64). XCD-swizzled.
__global__ __launch_bounds__(256) void k_conv1x1_qkv(
    const float* __restrict__ x, const float* __restrict__ w0,
    const float* __restrict__ w1, const float* __restrict__ w2,
    float* __restrict__ y)
{
  int lin = blockIdx.y * 18 + blockIdx.x;        // 0..1151
  int swz = (lin & 7) * 144 + (lin >> 3);        // 1152/8 = 144 per XCD
  int ntile = swz / 18;
  int r = swz - ntile * 18;
  int j = r / 6, otile = r - j * 6;
  const float* W = (j == 0) ? w0 : (j == 1) ? w1 : w2;
  gemm384_body(W, x, y + (size_t)j * PERT, otile, ntile);
}

// final: out_b = M_b @ v. grid = (6, 64)
__global__ __launch_bounds__(256) void k_gemm_final(
    const float* __restrict__ M, const float* __restrict__ v,
    float* __restrict__ out)
{
  int lin = blockIdx.y * 6 + blockIdx.x;         // 0..383
  int swz = (lin & 7) * 48 + (lin >> 3);
  int ntile = swz / 6, otile = swz - ntile * 6;
  gemm384_body(M, v, out, otile, ntile);
}

// depthwise 3x3 SAME. One thread per output element. Each block covers 256
// consecutive px of ONE plane (j,c) -> block-uniform plane, zero atomics:
// per-block sum-of-squares partial is written to partial[blockIdx.x].
__global__ __launch_bounds__(256) void k_dwconv(
    const float* __restrict__ Yin, const float* __restrict__ dw0,
    const float* __restrict__ dw1, const float* __restrict__ dw2,
    float* __restrict__ Zout, float* __restrict__ partial)
{
  __shared__ float red[4];
  int idx = blockIdx.x * 256 + threadIdx.x;      // over 3*384*16384
  int j = idx / (DIMC * HWN);
  int rem = idx - j * (DIMC * HWN);
  int c = rem >> 14;
  int n = rem & (HWN - 1);
  int h = n >> 7, w = n & (IMW - 1);
  const float* dw = ((j == 0) ? dw0 : (j == 1) ? dw1 : dw2) + c * 9;
  const float* src = Yin + (size_t)(j * DIMC + c) * HWN;
  float a = 0.f;
#pragma unroll
  for (int dy = -1; dy <= 1; ++dy) {
    int hh = h + dy;
    if (hh < 0 || hh >= IMW) continue;
#pragma unroll
    for (int dx = -1; dx <= 1; ++dx) {
      int ww = w + dx;
      if (ww < 0 || ww >= IMW) continue;
      a = fmaf(src[hh * IMW + ww], dw[(dy + 1) * 3 + (dx + 1)], a);
    }
  }
  Zout[idx] = a;
  if (j < 2) {                                   // block-uniform branch
    float s = a * a;
#pragma unroll
    for (int off = 32; off > 0; off >>= 1) s += __shfl_down(s, off);
    if ((threadIdx.x & 63) == 0) red[threadIdx.x >> 6] = s;
    __syncthreads();
    if (threadIdx.x == 0)
      partial[blockIdx.x] = red[0] + red[1] + red[2] + red[3];
  }
}

// Sraw[h][c][d] += sum_n q[h*48+c][n] * k[h*48+d][n]
__global__ __launch_bounds__(256) void k_qkdot(
    const float* __restrict__ q, const float* __restrict__ k,
    float* __restrict__ Sraw)
{
  int h = blockIdx.x & 7;
  int slice = blockIdx.x >> 3;
  int n0 = slice * 512;
  __shared__ float qs[64][49];   // [pixel][c], padded
  __shared__ float ks[64][49];
  int tid = threadIdx.x;
  int tc = tid >> 4, td = tid & 15;
  float acc[3][3];
#pragma unroll
  for (int i = 0; i < 3; ++i)
#pragma unroll
    for (int jj = 0; jj < 3; ++jj) acc[i][jj] = 0.f;

  const float* qb = q + (size_t)h * CHD * HWN;
  const float* kb = k + (size_t)h * CHD * HWN;
  for (int nn = n0; nn < n0 + 512; nn += 64) {
#pragma unroll
    for (int i = 0; i < 12; ++i) {               // 48*64/256 = 12 each
      int l = tid + i * 256;
      int c = l >> 6, p = l & 63;
      qs[p][c] = qb[(size_t)c * HWN + nn + p];
      ks[p][c] = kb[(size_t)c * HWN + nn + p];
    }
    __syncthreads();
#pragma unroll 8
    for (int p = 0; p < 64; ++p) {
      float qv[3], kv[3];
#pragma unroll
      for (int i = 0; i < 3; ++i) qv[i] = qs[p][tc * 3 + i];
#pragma unroll
      for (int i = 0; i < 3; ++i) kv[i] = ks[p][td * 3 + i];
#pragma unroll
      for (int i = 0; i < 3; ++i)
#pragma unroll
        for (int jj = 0; jj < 3; ++jj)
          acc[i][jj] = fmaf(qv[i], kv[jj], acc[i][jj]);
    }
    __syncthreads();
  }
#pragma unroll
  for (int i = 0; i < 3; ++i)
#pragma unroll
    for (int jj = 0; jj < 3; ++jj)
      atomicAdd(&Sraw[(h * CHD + tc * 3 + i) * CHD + td * 3 + jj], acc[i][jj]);
}

// softmax over d with fused L2-norm scaling. Thread t = row (h*48+c).
// Sums the 64 per-block dwconv partials per plane itself (planes 0..767).
__global__ __launch_bounds__(384) void k_softmax(
    const float* __restrict__ S, const float* __restrict__ partial,
    const float* __restrict__ temp, float* __restrict__ A)
{
  __shared__ float sk[DIMC];
  int t = threadIdx.x;
  float sq = 0.f, skk = 0.f;
#pragma unroll
  for (int s = 0; s < BLKS_PER_PLANE; ++s) {
    sq  += partial[t * BLKS_PER_PLANE + s];                    // plane t (q)
    skk += partial[(DIMC + t) * BLKS_PER_PLANE + s];           // plane 384+t (k)
  }
  sk[t] = 1.f / fmaxf(sqrtf(skk), 1e-12f);
  float invq = 1.f / fmaxf(sqrtf(sq), 1e-12f);
  __syncthreads();
  int h = t / CHD;
  float tp = temp[h];
  const float* Srow = S + t * CHD;
  float vals[CHD];
  float mx = -1e30f;
#pragma unroll
  for (int d = 0; d < CHD; ++d) {
    float v = Srow[d] * invq * sk[h * CHD + d] * tp;
    vals[d] = v;
    mx = fmaxf(mx, v);
  }
  float sum = 0.f;
#pragma unroll
  for (int d = 0; d < CHD; ++d) { vals[d] = expf(vals[d] - mx); sum += vals[d]; }
  float inv = 1.f / sum;
  float* Arow = A + t * CHD;
#pragma unroll
  for (int d = 0; d < CHD; ++d) Arow[d] = vals[d] * inv;
}

// M[o][dg] = sum_{c'} wproj[o][h(dg)*48+c'] * A[h(dg)][c'][d'(dg)]
__global__ __launch_bounds__(256) void k_combine(
    const float* __restrict__ wproj, const float* __restrict__ A,
    float* __restrict__ M)
{
  int idx = blockIdx.x * 256 + threadIdx.x;      // over 384*384
  int o = idx / DIMC;
  int dg = idx - o * DIMC;
  int h = dg / CHD, d = dg - h * CHD;
  const float* wrow = wproj + (size_t)o * DIMC + h * CHD;
  const float* Acol = A + (size_t)(h * CHD) * CHD + d;
  float s = 0.f;
#pragma unroll
  for (int c = 0; c < CHD; ++c)
    s = fmaf(wrow[c], Acol[c * CHD], s);
  M[idx] = s;
}

extern "C" void kernel_launch(void* const* d_in, const int* in_sizes, int n_in,
                              void* d_out, int out_size, void* d_ws, size_t ws_size,
                              hipStream_t stream)
{
  const float* x     = (const float*)d_in[0];
  const float* w0    = (const float*)d_in[1];
  const float* w1    = (const float*)d_in[2];
  const float* w2    = (const float*)d_in[3];
  const float* dw0   = (const float*)d_in[4];
  const float* dw1   = (const float*)d_in[5];
  const float* dw2   = (const float*)d_in[6];
  const float* wproj = (const float*)d_in[7];
  const float* temp  = (const float*)d_in[8];
  float* out = (float*)d_out;

  float* qkv0    = (float*)d_ws;                     // 3*PERT
  float* qkv     = qkv0 + 3 * PERT;                  // 3*PERT (q,k,v)
  float* Sraw    = qkv + 3 * PERT;                   // 8*48*48
  float* partial = Sraw + NHEADS * CHD * CHD;        // 1152*64 block partials
  float* Aat     = partial + NPLANES * BLKS_PER_PLANE;
  float* Mm      = Aat + NHEADS * CHD * CHD;         // 384*384

  for (int b = 0; b < 8; ++b) {
    const float* xb = x + (size_t)b * PERT;
    float* outb = out + (size_t)b * PERT;
    hipMemsetAsync(Sraw, 0, NHEADS * CHD * CHD * sizeof(float), stream);
    k_conv1x1_qkv<<<dim3(18, 64), 256, 0, stream>>>(xb, w0, w1, w2, qkv0);
    k_dwconv<<<NPLANES * BLKS_PER_PLANE, 256, 0, stream>>>(qkv0, dw0, dw1, dw2, qkv, partial);
    k_qkdot<<<256, 256, 0, stream>>>(qkv, qkv + PERT, Sraw);
    k_softmax<<<1, DIMC, 0, stream>>>(Sraw, partial, temp, Aat);
    k_combine<<<(DIMC * DIMC) / 256, 256, 0, stream>>>(wproj, Aat, Mm);
    k_gemm_final<<<dim3(6, 64), 256, 0, stream>>>(Mm, qkv + 2 * PERT, outb);
  }
  (void)in_sizes; (void)n_in; (void)out_size; (void)ws_size;
}

// Round 3
// 1168.726 us; speedup vs baseline: 4.4044x; 2.8395x over previous
//
#include <hip/hip_runtime.h>
#include <math.h>

#define DIMC 384
#define NHEADS 8
#define CHD 48
#define HWN 16384
#define IMW 128
#define PERT ((size_t)DIMC * HWN)   // elements per [384,128,128] tensor
#define WELEM (DIMC * DIMC)         // 147456

typedef short short8 __attribute__((ext_vector_type(8)));
typedef unsigned short u16x8 __attribute__((ext_vector_type(8)));
typedef float f32x4 __attribute__((ext_vector_type(4)));

__device__ __forceinline__ unsigned short f2bf(float f) {
  unsigned int u = __float_as_uint(f);
  unsigned int r = (u + 0x7fffu + ((u >> 16) & 1u)) >> 16;   // RNE
  return (unsigned short)r;
}
__device__ __forceinline__ float bf2f(unsigned short b) {
  return __uint_as_float(((unsigned int)b) << 16);
}
__device__ __forceinline__ void async16(const void* g, void* l) {
  __builtin_amdgcn_global_load_lds(
      (const __attribute__((address_space(1))) void*)g,
      (__attribute__((address_space(3))) void*)l, 16, 0, 0);
}

// ---------------------------------------------------------------------------
// bf16 MFMA GEMM: Y[128m x 128n tile] = A[384x384] @ B, B given as swizzled
// B^T (BT[n][k], row byte ^= (n&7)<<4 within 128B spans). 4 waves, BK=64.
// A-frags read straight from global (L2-resident). OUTBF: bf16 vs f32 out.
// ---------------------------------------------------------------------------
template <int OUTBF>
__device__ __forceinline__ void mfma_gemm(
    const unsigned short* __restrict__ A,
    const unsigned short* __restrict__ BT,
    void* __restrict__ Y, int obase, int nbase)
{
  __shared__ unsigned short Bs[128 * 64];   // 16 KB, swizzled rows
  const int tid = threadIdx.x;
  const int lane = tid & 63;
  const int wv = tid >> 6;
  const int wm = (wv >> 1) * 64;
  const int wn = (wv & 1) * 64;

  f32x4 acc[4][4];
#pragma unroll
  for (int i = 0; i < 4; ++i)
#pragma unroll
    for (int j = 0; j < 4; ++j) acc[i][j] = (f32x4){0.f, 0.f, 0.f, 0.f};

  // staging geometry: slot s=(tid+i*256)*16B -> n=tid/8+i*32, kbyte=(tid%8)*16
  const int nrow = tid >> 3;
  const int kbyte = (tid & 7) * 16;
  const unsigned short* bsrc = BT + (size_t)(nbase + nrow) * DIMC + (kbyte >> 1);

  const int arow = obase + wm + (lane & 15);
  const int akoff = (lane >> 4) << 3;       // elements
  const int nb_l = wn + (lane & 15);
  const int kg16 = (lane >> 4) << 4;        // bytes
  const int sw = (lane & 7) << 4;           // bytes (row XOR swizzle)

  for (int k0 = 0; k0 < DIMC; k0 += 64) {
#pragma unroll
    for (int i = 0; i < 4; ++i)
      async16(bsrc + (size_t)(i * 32) * DIMC + k0,
              &Bs[(wv * 64 + i * 256) * 8]);
    short8 af[2][4];
#pragma unroll
    for (int kq = 0; kq < 2; ++kq)
#pragma unroll
      for (int mi = 0; mi < 4; ++mi)
        af[kq][mi] = *reinterpret_cast<const short8*>(
            &A[(size_t)(arow + mi * 16) * DIMC + k0 + kq * 32 + akoff]);
    __syncthreads();
#pragma unroll
    for (int kq = 0; kq < 2; ++kq) {
      const int boff = ((kq * 64 + kg16) ^ sw) >> 1;   // shorts
      short8 bf[4];
#pragma unroll
      for (int ni = 0; ni < 4; ++ni)
        bf[ni] = *reinterpret_cast<const short8*>(
            &Bs[(nb_l + ni * 16) * 64 + boff]);
#pragma unroll
      for (int mi = 0; mi < 4; ++mi)
#pragma unroll
        for (int ni = 0; ni < 4; ++ni)
          acc[mi][ni] = __builtin_amdgcn_mfma_f32_16x16x32_bf16(
              af[kq][mi], bf[ni], acc[mi][ni], 0, 0, 0);
    }
    __syncthreads();
  }
  const int orow = obase + wm + ((lane >> 4) << 2);
  const int ocol = nbase + wn + (lane & 15);
#pragma unroll
  for (int mi = 0; mi < 4; ++mi)
#pragma unroll
    for (int ni = 0; ni < 4; ++ni)
#pragma unroll
      for (int r = 0; r < 4; ++r) {
        size_t off = (size_t)(orow + mi * 16 + r) * HWN + ocol + ni * 16;
        if (OUTBF) ((unsigned short*)Y)[off] = f2bf(acc[mi][ni][r]);
        else       ((float*)Y)[off] = acc[mi][ni][r];
      }
}

// q0k0v0 = {w0,w1,w2} @ x. grid (9,128): 9 = 3 j x 3 mtile. XCD swizzle keeps
// the 9 (j,mt) blocks of one n-tile adjacent -> B-tile L2 reuse.
__global__ __launch_bounds__(256) void k_conv_mfma(
    const unsigned short* __restrict__ Wc, const unsigned short* __restrict__ XT,
    unsigned short* __restrict__ Y)
{
  int lin = blockIdx.y * 9 + blockIdx.x;         // 0..1151
  int swz = (lin & 7) * 144 + (lin >> 3);
  int nt = swz / 9, r = swz - nt * 9;
  int j = r / 3, mt = r - j * 3;
  mfma_gemm<1>(Wc + j * WELEM, XT, Y + (size_t)j * PERT, mt * 128, nt * 128);
}

__global__ __launch_bounds__(256) void k_final_mfma(
    const unsigned short* __restrict__ M, const unsigned short* __restrict__ vT,
    float* __restrict__ out)
{
  int lin = blockIdx.y * 3 + blockIdx.x;         // 0..383
  int swz = (lin & 7) * 48 + (lin >> 3);
  int nt = swz / 3, mt = swz - nt * 3;
  mfma_gemm<0>(M, vT, out, mt * 128, nt * 128);
}

// transpose+convert x[c][n] f32 -> XT[n][c] bf16, rows XOR-swizzled.
__global__ __launch_bounds__(256) void k_transpose_x(
    const float* __restrict__ x, unsigned short* __restrict__ XT)
{
  __shared__ unsigned short S[64][72];
  int n0 = blockIdx.x * 64, c0 = blockIdx.y * 64;
  int t = threadIdx.x;
  int cl = t >> 2, ns = (t & 3) * 16;
  const float* src = &x[(size_t)(c0 + cl) * HWN + n0 + ns];
#pragma unroll
  for (int i = 0; i < 16; i += 4) {
    float4 v = *reinterpret_cast<const float4*>(&src[i]);
    S[cl][ns + i + 0] = f2bf(v.x);
    S[cl][ns + i + 1] = f2bf(v.y);
    S[cl][ns + i + 2] = f2bf(v.z);
    S[cl][ns + i + 3] = f2bf(v.w);
  }
  __syncthreads();
  int nl = t >> 2, cs = (t & 3) * 16;
  unsigned short tmp[16];
#pragma unroll
  for (int i = 0; i < 16; ++i) tmp[i] = S[cs + i][nl];
  u16x8 p0, p1;
#pragma unroll
  for (int i = 0; i < 8; ++i) { p0[i] = tmp[i]; p1[i] = tmp[8 + i]; }
  char* rowb = (char*)XT + (size_t)(n0 + nl) * (DIMC * 2);
  int cb = (c0 + cs) * 2;
  int sw = (nl & 7) << 4;
  *reinterpret_cast<u16x8*>(rowb + ((cb) ^ sw)) = p0;
  *reinterpret_cast<u16x8*>(rowb + ((cb + 16) ^ sw)) = p1;
}

// transpose v[c][n] bf16 -> vT[n][c] bf16, same swizzle.
__global__ __launch_bounds__(256) void k_transpose_v(
    const unsigned short* __restrict__ v, unsigned short* __restrict__ vT)
{
  __shared__ unsigned short S[64][72];
  int n0 = blockIdx.x * 64, c0 = blockIdx.y * 64;
  int t = threadIdx.x;
  int cl = t >> 2, ns = (t & 3) * 16;
  const unsigned short* src = &v[(size_t)(c0 + cl) * HWN + n0 + ns];
  *reinterpret_cast<u16x8*>(&S[cl][ns]) = *reinterpret_cast<const u16x8*>(&src[0]);
  *reinterpret_cast<u16x8*>(&S[cl][ns + 8]) = *reinterpret_cast<const u16x8*>(&src[8]);
  __syncthreads();
  int nl = t >> 2, cs = (t & 3) * 16;
  unsigned short tmp[16];
#pragma unroll
  for (int i = 0; i < 16; ++i) tmp[i] = S[cs + i][nl];
  u16x8 p0, p1;
#pragma unroll
  for (int i = 0; i < 8; ++i) { p0[i] = tmp[i]; p1[i] = tmp[8 + i]; }
  char* rowb = (char*)vT + (size_t)(n0 + nl) * (DIMC * 2);
  int cb = (c0 + cs) * 2;
  int sw = (nl & 7) << 4;
  *reinterpret_cast<u16x8*>(rowb + ((cb) ^ sw)) = p0;
  *reinterpret_cast<u16x8*>(rowb + ((cb + 16) ^ sw)) = p1;
}

__global__ __launch_bounds__(256) void k_convert_w(
    const float* __restrict__ w0, const float* __restrict__ w1,
    const float* __restrict__ w2, unsigned short* __restrict__ Wc)
{
  int idx = blockIdx.x * 256 + threadIdx.x;      // < 3*147456
  int j = idx / WELEM, r = idx - j * WELEM;
  const float* s = (j == 0) ? w0 : (j == 1) ? w1 : w2;
  Wc[idx] = f2bf(s[r]);
}

// depthwise 3x3 SAME, bf16 in/out, 8 px per thread along w; fused per-block
// sum-of-squares partial (8 blocks per plane, block-uniform plane).
__global__ __launch_bounds__(256) void k_dwconv(
    const unsigned short* __restrict__ Yin, const float* __restrict__ dw0,
    const float* __restrict__ dw1, const float* __restrict__ dw2,
    unsigned short* __restrict__ Zout, float* __restrict__ partial)
{
  __shared__ float red[4];
  int gid = blockIdx.x * 256 + threadIdx.x;
  int plane = gid >> 11;                 // 2048 units/plane
  int rem = gid & 2047;
  int j = plane / DIMC;
  int c = plane - j * DIMC;
  int h = rem >> 4;
  int w0p = (rem & 15) << 3;
  const float* dw = ((j == 0) ? dw0 : (j == 1) ? dw1 : dw2) + c * 9;
  const unsigned short* src = Yin + (size_t)plane * HWN;
  float a[8] = {0.f, 0.f, 0.f, 0.f, 0.f, 0.f, 0.f, 0.f};
#pragma unroll
  for (int dy = -1; dy <= 1; ++dy) {
    int hh = h + dy;
    if (hh < 0 || hh >= IMW) continue;
    const unsigned short* row = src + hh * IMW;
    u16x8 m = *reinterpret_cast<const u16x8*>(&row[w0p]);
    float mf[8];
#pragma unroll
    for (int i = 0; i < 8; ++i) mf[i] = bf2f(m[i]);
    float lf = (w0p > 0) ? bf2f(row[w0p - 1]) : 0.f;
    float rf = (w0p < 120) ? bf2f(row[w0p + 8]) : 0.f;
    float t0 = dw[(dy + 1) * 3], t1 = dw[(dy + 1) * 3 + 1], t2 = dw[(dy + 1) * 3 + 2];
    a[0] += lf * t0 + mf[0] * t1 + mf[1] * t2;
#pragma unroll
    for (int i = 1; i < 7; ++i)
      a[i] += mf[i - 1] * t0 + mf[i] * t1 + mf[i + 1] * t2;
    a[7] += mf[6] * t0 + mf[7] * t1 + rf * t2;
  }
  u16x8 o;
#pragma unroll
  for (int i = 0; i < 8; ++i) o[i] = f2bf(a[i]);
  *reinterpret_cast<u16x8*>(&Zout[(size_t)plane * HWN + h * IMW + w0p]) = o;
  if (j < 2) {
    float s = 0.f;
#pragma unroll
    for (int i = 0; i < 8; ++i) s += a[i] * a[i];
#pragma unroll
    for (int off = 32; off > 0; off >>= 1) s += __shfl_down(s, off);
    if ((threadIdx.x & 63) == 0) red[threadIdx.x >> 6] = s;
    __syncthreads();
    if (threadIdx.x == 0)
      partial[blockIdx.x] = red[0] + red[1] + red[2] + red[3];
  }
}

// Sraw[h][c][d] += sum_n q[h*48+c][n] * k[h*48+d][n]  (bf16 inputs)
__global__ __launch_bounds__(256) void k_qkdot(
    const unsigned short* __restrict__ q, const unsigned short* __restrict__ k,
    float* __restrict__ Sraw)
{
  int h = blockIdx.x & 7;
  int slice = blockIdx.x >> 3;
  int n0 = slice * 512;
  __shared__ float qs[64][49];
  __shared__ float ks[64][49];
  int tid = threadIdx.x;
  int tc = tid >> 4, td = tid & 15;
  float acc[3][3];
#pragma unroll
  for (int i = 0; i < 3; ++i)
#pragma unroll
    for (int jj = 0; jj < 3; ++jj) acc[i][jj] = 0.f;

  const unsigned short* qb = q + (size_t)h * CHD * HWN;
  const unsigned short* kb = k + (size_t)h * CHD * HWN;
  for (int nn = n0; nn < n0 + 512; nn += 64) {
#pragma unroll
    for (int i = 0; i < 12; ++i) {
      int l = tid + i * 256;
      int c = l >> 6, p = l & 63;
      qs[p][c] = bf2f(qb[(size_t)c * HWN + nn + p]);
      ks[p][c] = bf2f(kb[(size_t)c * HWN + nn + p]);
    }
    __syncthreads();
#pragma unroll 8
    for (int p = 0; p < 64; ++p) {
      float qv[3], kv[3];
#pragma unroll
      for (int i = 0; i < 3; ++i) qv[i] = qs[p][tc * 3 + i];
#pragma unroll
      for (int i = 0; i < 3; ++i) kv[i] = ks[p][td * 3 + i];
#pragma unroll
      for (int i = 0; i < 3; ++i)
#pragma unroll
        for (int jj = 0; jj < 3; ++jj)
          acc[i][jj] = fmaf(qv[i], kv[jj], acc[i][jj]);
    }
    __syncthreads();
  }
#pragma unroll
  for (int i = 0; i < 3; ++i)
#pragma unroll
    for (int jj = 0; jj < 3; ++jj)
      atomicAdd(&Sraw[(h * CHD + tc * 3 + i) * CHD + td * 3 + jj], acc[i][jj]);
}

// softmax over d with fused L2-norm scaling; sums 8 dwconv partials/plane.
__global__ __launch_bounds__(384) void k_softmax(
    const float* __restrict__ S, const float* __restrict__ partial,
    const float* __restrict__ temp, float* __restrict__ A)
{
  __shared__ float sk[DIMC];
  int t = threadIdx.x;
  float sq = 0.f, skk = 0.f;
#pragma unroll
  for (int s = 0; s < 8; ++s) {
    sq  += partial[t * 8 + s];
    skk += partial[(DIMC + t) * 8 + s];
  }
  sk[t] = 1.f / fmaxf(sqrtf(skk), 1e-12f);
  float invq = 1.f / fmaxf(sqrtf(sq), 1e-12f);
  __syncthreads();
  int h = t / CHD;
  float tp = temp[h];
  const float* Srow = S + t * CHD;
  float vals[CHD];
  float mx = -1e30f;
#pragma unroll
  for (int d = 0; d < CHD; ++d) {
    float v = Srow[d] * invq * sk[h * CHD + d] * tp;
    vals[d] = v;
    mx = fmaxf(mx, v);
  }
  float sum = 0.f;
#pragma unroll
  for (int d = 0; d < CHD; ++d) { vals[d] = expf(vals[d] - mx); sum += vals[d]; }
  float inv = 1.f / sum;
  float* Arow = A + t * CHD;
#pragma unroll
  for (int d = 0; d < CHD; ++d) Arow[d] = vals[d] * inv;
}

// M[o][dg] = sum_{c'} wproj[o][h*48+c'] * A[h][c'][d'],  bf16 output.
__global__ __launch_bounds__(256) void k_combine(
    const float* __restrict__ wproj, const float* __restrict__ A,
    unsigned short* __restrict__ M)
{
  int idx = blockIdx.x * 256 + threadIdx.x;      // over 384*384
  int o = idx / DIMC;
  int dg = idx - o * DIMC;
  int h = dg / CHD, d = dg - h * CHD;
  const float* wrow = wproj + (size_t)o * DIMC + h * CHD;
  const float* Acol = A + (size_t)(h * CHD) * CHD + d;
  float s = 0.f;
#pragma unroll
  for (int c = 0; c < CHD; ++c)
    s = fmaf(wrow[c], Acol[c * CHD], s);
  M[idx] = f2bf(s);
}

extern "C" void kernel_launch(void* const* d_in, const int* in_sizes, int n_in,
                              void* d_out, int out_size, void* d_ws, size_t ws_size,
                              hipStream_t stream)
{
  const float* x     = (const float*)d_in[0];
  const float* w0    = (const float*)d_in[1];
  const float* w1    = (const float*)d_in[2];
  const float* w2    = (const float*)d_in[3];
  const float* dw0   = (const float*)d_in[4];
  const float* dw1   = (const float*)d_in[5];
  const float* dw2   = (const float*)d_in[6];
  const float* wproj = (const float*)d_in[7];
  const float* temp  = (const float*)d_in[8];
  float* out = (float*)d_out;

  // ws layout (bytes, 256-aligned chunks)
  char* p = (char*)d_ws;
  unsigned short* Wc    = (unsigned short*)p;  p += ((size_t)3 * WELEM * 2 + 255) / 256 * 256;
  unsigned short* XT    = (unsigned short*)p;  p += (PERT * 2 + 255) / 256 * 256;
  unsigned short* q0k0v0= (unsigned short*)p;  p += (3 * PERT * 2 + 255) / 256 * 256;
  unsigned short* qkv   = (unsigned short*)p;  p += (3 * PERT * 2 + 255) / 256 * 256;
  unsigned short* vT    = (unsigned short*)p;  p += (PERT * 2 + 255) / 256 * 256;
  float* Sraw    = (float*)p;  p += (NHEADS * CHD * CHD * 4 + 255) / 256 * 256;
  float* partial = (float*)p;  p += ((size_t)3 * DIMC * 8 * 4 + 255) / 256 * 256;
  float* Aat     = (float*)p;  p += (NHEADS * CHD * CHD * 4 + 255) / 256 * 256;
  unsigned short* Mbf = (unsigned short*)p;

  k_convert_w<<<(3 * WELEM + 255) / 256, 256, 0, stream>>>(w0, w1, w2, Wc);

  for (int b = 0; b < 8; ++b) {
    const float* xb = x + (size_t)b * PERT;
    float* outb = out + (size_t)b * PERT;
    k_transpose_x<<<dim3(256, 6), 256, 0, stream>>>(xb, XT);
    k_conv_mfma<<<dim3(9, 128), 256, 0, stream>>>(Wc, XT, q0k0v0);
    k_dwconv<<<3 * DIMC * 8, 256, 0, stream>>>(q0k0v0, dw0, dw1, dw2, qkv, partial);
    k_transpose_v<<<dim3(256, 6), 256, 0, stream>>>(qkv + 2 * PERT, vT);
    hipMemsetAsync(Sraw, 0, NHEADS * CHD * CHD * sizeof(float), stream);
    k_qkdot<<<256, 256, 0, stream>>>(qkv, qkv + PERT, Sraw);
    k_softmax<<<1, DIMC, 0, stream>>>(Sraw, partial, temp, Aat);
    k_combine<<<(DIMC * DIMC) / 256, 256, 0, stream>>>(wproj, Aat, Mbf);
    k_final_mfma<<<dim3(3, 128), 256, 0, stream>>>(Mbf, vT, outb);
  }
  (void)in_sizes; (void)n_in; (void)out_size; (void)ws_size;
}

// Round 4
// 838.248 us; speedup vs baseline: 6.1408x; 1.3942x over previous
//
#include <hip/hip_runtime.h>
#include <math.h>

#define DIMC 384
#define NHEADS 8
#define CHD 48
#define HWN 16384
#define IMW 128
#define PERT ((size_t)DIMC * HWN)   // elements per [384,128,128] tensor
#define WELEM (DIMC * DIMC)         // 147456
#define NB 8

typedef short short8 __attribute__((ext_vector_type(8)));
typedef unsigned short u16x8 __attribute__((ext_vector_type(8)));
typedef float f32x4 __attribute__((ext_vector_type(4)));

__device__ __forceinline__ unsigned short f2bf(float f) {
  unsigned int u = __float_as_uint(f);
  unsigned int r = (u + 0x7fffu + ((u >> 16) & 1u)) >> 16;   // RNE
  return (unsigned short)r;
}
__device__ __forceinline__ float bf2f(unsigned short b) {
  return __uint_as_float(((unsigned int)b) << 16);
}
__device__ __forceinline__ void async16(const void* g, void* l) {
  __builtin_amdgcn_global_load_lds(
      (const __attribute__((address_space(1))) void*)g,
      (__attribute__((address_space(3))) void*)l, 16, 0, 0);
}

// ---------------------------------------------------------------------------
// bf16 MFMA GEMM: Y[128m x 128n tile] = A[384x384] @ B, B given as swizzled
// B^T (BT[n][k], row byte ^= (n&7)<<4 within 128B spans). 4 waves, BK=64.
// A-frags read straight from global (L2-resident). OUTBF: bf16 vs f32 out.
// ---------------------------------------------------------------------------
template <int OUTBF>
__device__ __forceinline__ void mfma_gemm(
    const unsigned short* __restrict__ A,
    const unsigned short* __restrict__ BT,
    void* __restrict__ Y, int obase, int nbase)
{
  __shared__ unsigned short Bs[128 * 64];   // 16 KB, swizzled rows
  const int tid = threadIdx.x;
  const int lane = tid & 63;
  const int wv = tid >> 6;
  const int wm = (wv >> 1) * 64;
  const int wn = (wv & 1) * 64;

  f32x4 acc[4][4];
#pragma unroll
  for (int i = 0; i < 4; ++i)
#pragma unroll
    for (int j = 0; j < 4; ++j) acc[i][j] = (f32x4){0.f, 0.f, 0.f, 0.f};

  const int nrow = tid >> 3;
  const int kbyte = (tid & 7) * 16;
  const unsigned short* bsrc = BT + (size_t)(nbase + nrow) * DIMC + (kbyte >> 1);

  const int arow = obase + wm + (lane & 15);
  const int akoff = (lane >> 4) << 3;       // elements
  const int nb_l = wn + (lane & 15);
  const int kg16 = (lane >> 4) << 4;        // bytes
  const int sw = (lane & 7) << 4;           // bytes (row XOR swizzle)

  for (int k0 = 0; k0 < DIMC; k0 += 64) {
#pragma unroll
    for (int i = 0; i < 4; ++i)
      async16(bsrc + (size_t)(i * 32) * DIMC + k0,
              &Bs[(wv * 64 + i * 256) * 8]);
    short8 af[2][4];
#pragma unroll
    for (int kq = 0; kq < 2; ++kq)
#pragma unroll
      for (int mi = 0; mi < 4; ++mi)
        af[kq][mi] = *reinterpret_cast<const short8*>(
            &A[(size_t)(arow + mi * 16) * DIMC + k0 + kq * 32 + akoff]);
    __syncthreads();
#pragma unroll
    for (int kq = 0; kq < 2; ++kq) {
      const int boff = ((kq * 64 + kg16) ^ sw) >> 1;   // shorts
      short8 bf[4];
#pragma unroll
      for (int ni = 0; ni < 4; ++ni)
        bf[ni] = *reinterpret_cast<const short8*>(
            &Bs[(nb_l + ni * 16) * 64 + boff]);
#pragma unroll
      for (int mi = 0; mi < 4; ++mi)
#pragma unroll
        for (int ni = 0; ni < 4; ++ni)
          acc[mi][ni] = __builtin_amdgcn_mfma_f32_16x16x32_bf16(
              af[kq][mi], bf[ni], acc[mi][ni], 0, 0, 0);
    }
    __syncthreads();
  }
  const int orow = obase + wm + ((lane >> 4) << 2);
  const int ocol = nbase + wn + (lane & 15);
#pragma unroll
  for (int mi = 0; mi < 4; ++mi)
#pragma unroll
    for (int ni = 0; ni < 4; ++ni)
#pragma unroll
      for (int r = 0; r < 4; ++r) {
        size_t off = (size_t)(orow + mi * 16 + r) * HWN + ocol + ni * 16;
        if (OUTBF) ((unsigned short*)Y)[off] = f2bf(acc[mi][ni][r]);
        else       ((float*)Y)[off] = acc[mi][ni][r];
      }
}

// q0k0v0[b] = {w0,w1,w2} @ x[b]. grid (9,128,8). XCD swizzle over 9216 blocks.
__global__ __launch_bounds__(256) void k_conv_mfma(
    const unsigned short* __restrict__ Wc, const unsigned short* __restrict__ XT,
    unsigned short* __restrict__ Y)
{
  int lin = ((int)blockIdx.z * 128 + blockIdx.y) * 9 + blockIdx.x;  // 0..9215
  int swz = (lin & 7) * 1152 + (lin >> 3);
  int g = swz / 9, r = swz - g * 9;      // g = b*128 + nt
  int bb = g >> 7, nt = g & 127;
  int j = r / 3, mt = r - j * 3;
  mfma_gemm<1>(Wc + j * WELEM, XT + (size_t)bb * PERT,
               Y + (size_t)bb * 3 * PERT + (size_t)j * PERT, mt * 128, nt * 128);
}

// out[b] = M[b] @ v[b]. grid (3,128,8).
__global__ __launch_bounds__(256) void k_final_mfma(
    const unsigned short* __restrict__ M, const unsigned short* __restrict__ vT,
    float* __restrict__ out)
{
  int lin = ((int)blockIdx.z * 128 + blockIdx.y) * 3 + blockIdx.x;  // 0..3071
  int swz = (lin & 7) * 384 + (lin >> 3);
  int g = swz / 3, mt = swz - g * 3;
  int bb = g >> 7, nt = g & 127;
  mfma_gemm<0>(M + (size_t)bb * WELEM, vT + (size_t)bb * PERT,
               out + (size_t)bb * PERT, mt * 128, nt * 128);
}

// transpose+convert x[b][c][n] f32 -> XT[b][n][c] bf16, rows XOR-swizzled.
__global__ __launch_bounds__(256) void k_transpose_x(
    const float* __restrict__ x, unsigned short* __restrict__ XT)
{
  __shared__ unsigned short S[64][72];
  int n0 = blockIdx.x * 64, c0 = blockIdx.y * 64;
  const float* xb = x + (size_t)blockIdx.z * PERT;
  unsigned short* XTb = XT + (size_t)blockIdx.z * PERT;
  int t = threadIdx.x;
  int cl = t >> 2, ns = (t & 3) * 16;
  const float* src = &xb[(size_t)(c0 + cl) * HWN + n0 + ns];
#pragma unroll
  for (int i = 0; i < 16; i += 4) {
    float4 v = *reinterpret_cast<const float4*>(&src[i]);
    S[cl][ns + i + 0] = f2bf(v.x);
    S[cl][ns + i + 1] = f2bf(v.y);
    S[cl][ns + i + 2] = f2bf(v.z);
    S[cl][ns + i + 3] = f2bf(v.w);
  }
  __syncthreads();
  int nl = t >> 2, cs = (t & 3) * 16;
  unsigned short tmp[16];
#pragma unroll
  for (int i = 0; i < 16; ++i) tmp[i] = S[cs + i][nl];
  u16x8 p0, p1;
#pragma unroll
  for (int i = 0; i < 8; ++i) { p0[i] = tmp[i]; p1[i] = tmp[8 + i]; }
  char* rowb = (char*)XTb + (size_t)(n0 + nl) * (DIMC * 2);
  int cb = (c0 + cs) * 2;
  int sw = (nl & 7) << 4;
  *reinterpret_cast<u16x8*>(rowb + ((cb) ^ sw)) = p0;
  *reinterpret_cast<u16x8*>(rowb + ((cb + 16) ^ sw)) = p1;
}

// transpose v[b][c][n] bf16 -> vT[b][n][c] bf16, same swizzle.
__global__ __launch_bounds__(256) void k_transpose_v(
    const unsigned short* __restrict__ qkv, unsigned short* __restrict__ vT)
{
  __shared__ unsigned short S[64][72];
  int n0 = blockIdx.x * 64, c0 = blockIdx.y * 64;
  const unsigned short* v = qkv + (size_t)blockIdx.z * 3 * PERT + 2 * PERT;
  unsigned short* vTb = vT + (size_t)blockIdx.z * PERT;
  int t = threadIdx.x;
  int cl = t >> 2, ns = (t & 3) * 16;
  const unsigned short* src = &v[(size_t)(c0 + cl) * HWN + n0 + ns];
  *reinterpret_cast<u16x8*>(&S[cl][ns]) = *reinterpret_cast<const u16x8*>(&src[0]);
  *reinterpret_cast<u16x8*>(&S[cl][ns + 8]) = *reinterpret_cast<const u16x8*>(&src[8]);
  __syncthreads();
  int nl = t >> 2, cs = (t & 3) * 16;
  unsigned short tmp[16];
#pragma unroll
  for (int i = 0; i < 16; ++i) tmp[i] = S[cs + i][nl];
  u16x8 p0, p1;
#pragma unroll
  for (int i = 0; i < 8; ++i) { p0[i] = tmp[i]; p1[i] = tmp[8 + i]; }
  char* rowb = (char*)vTb + (size_t)(n0 + nl) * (DIMC * 2);
  int cb = (c0 + cs) * 2;
  int sw = (nl & 7) << 4;
  *reinterpret_cast<u16x8*>(rowb + ((cb) ^ sw)) = p0;
  *reinterpret_cast<u16x8*>(rowb + ((cb + 16) ^ sw)) = p1;
}

__global__ __launch_bounds__(256) void k_convert_w(
    const float* __restrict__ w0, const float* __restrict__ w1,
    const float* __restrict__ w2, unsigned short* __restrict__ Wc)
{
  int idx = blockIdx.x * 256 + threadIdx.x;      // < 3*147456
  int j = idx / WELEM, r = idx - j * WELEM;
  const float* s = (j == 0) ? w0 : (j == 1) ? w1 : w2;
  Wc[idx] = f2bf(s[r]);
}

// depthwise 3x3 SAME, bf16 in/out, 8 px per thread; per-block sum-of-squares
// partial (8 blocks per plane). planes: [b][j][c], 9216 total.
__global__ __launch_bounds__(256) void k_dwconv(
    const unsigned short* __restrict__ Yin, const float* __restrict__ dw0,
    const float* __restrict__ dw1, const float* __restrict__ dw2,
    unsigned short* __restrict__ Zout, float* __restrict__ partial)
{
  __shared__ float red[4];
  int gid = blockIdx.x * 256 + threadIdx.x;
  int plane = gid >> 11;                 // 2048 8px-units per plane
  int rem = gid & 2047;
  int pl = plane % (3 * DIMC);
  int j = pl / DIMC;
  int c = pl - j * DIMC;
  int h = rem >> 4;
  int w0p = (rem & 15) << 3;
  const float* dw = ((j == 0) ? dw0 : (j == 1) ? dw1 : dw2) + c * 9;
  const unsigned short* src = Yin + (size_t)plane * HWN;
  float a[8] = {0.f, 0.f, 0.f, 0.f, 0.f, 0.f, 0.f, 0.f};
#pragma unroll
  for (int dy = -1; dy <= 1; ++dy) {
    int hh = h + dy;
    if (hh < 0 || hh >= IMW) continue;
    const unsigned short* row = src + hh * IMW;
    u16x8 m = *reinterpret_cast<const u16x8*>(&row[w0p]);
    float mf[8];
#pragma unroll
    for (int i = 0; i < 8; ++i) mf[i] = bf2f(m[i]);
    float lf = (w0p > 0) ? bf2f(row[w0p - 1]) : 0.f;
    float rf = (w0p < 120) ? bf2f(row[w0p + 8]) : 0.f;
    float t0 = dw[(dy + 1) * 3], t1 = dw[(dy + 1) * 3 + 1], t2 = dw[(dy + 1) * 3 + 2];
    a[0] += lf * t0 + mf[0] * t1 + mf[1] * t2;
#pragma unroll
    for (int i = 1; i < 7; ++i)
      a[i] += mf[i - 1] * t0 + mf[i] * t1 + mf[i + 1] * t2;
    a[7] += mf[6] * t0 + mf[7] * t1 + rf * t2;
  }
  u16x8 o;
#pragma unroll
  for (int i = 0; i < 8; ++i) o[i] = f2bf(a[i]);
  *reinterpret_cast<u16x8*>(&Zout[(size_t)plane * HWN + h * IMW + w0p]) = o;
  if (j < 2) {
    float s = 0.f;
#pragma unroll
    for (int i = 0; i < 8; ++i) s += a[i] * a[i];
#pragma unroll
    for (int off = 32; off > 0; off >>= 1) s += __shfl_down(s, off);
    if ((threadIdx.x & 63) == 0) red[threadIdx.x >> 6] = s;
    __syncthreads();
    if (threadIdx.x == 0)
      partial[blockIdx.x] = red[0] + red[1] + red[2] + red[3];
  }
}

// Fused S = q@k^T (MFMA, frags straight from global) + L2-norm scale +
// softmax. grid = 64 blocks (b*8+h), 512 threads = 8 waves (n-partitioned).
__global__ __launch_bounds__(512) void k_attn(
    const unsigned short* __restrict__ qkv, const float* __restrict__ partial,
    const float* __restrict__ temp, float* __restrict__ Aat)
{
  __shared__ float Sred[4][48][48];      // 36.9 KB
  __shared__ float invq[48], invk[48];
  int b = blockIdx.x >> 3, h = blockIdx.x & 7;
  int tid = threadIdx.x, lane = tid & 63, w = tid >> 6;
  const unsigned short* qb = qkv + ((size_t)b * 3 * DIMC + h * CHD) * HWN;
  const unsigned short* kb = qb + (size_t)DIMC * HWN;
  const int row = lane & 15;
  const int ko = (lane >> 4) << 3;
  const int n0 = w * 2048;

  f32x4 acc[3][3];
#pragma unroll
  for (int i = 0; i < 3; ++i)
#pragma unroll
    for (int j = 0; j < 3; ++j) acc[i][j] = (f32x4){0.f, 0.f, 0.f, 0.f};

  for (int ns = n0; ns < n0 + 2048; ns += 32) {
    short8 aq[3], bk[3];
#pragma unroll
    for (int mi = 0; mi < 3; ++mi)
      aq[mi] = *reinterpret_cast<const short8*>(&qb[(size_t)(mi * 16 + row) * HWN + ns + ko]);
#pragma unroll
    for (int ni = 0; ni < 3; ++ni)
      bk[ni] = *reinterpret_cast<const short8*>(&kb[(size_t)(ni * 16 + row) * HWN + ns + ko]);
#pragma unroll
    for (int mi = 0; mi < 3; ++mi)
#pragma unroll
      for (int ni = 0; ni < 3; ++ni)
        acc[mi][ni] = __builtin_amdgcn_mfma_f32_16x16x32_bf16(
            aq[mi], bk[ni], acc[mi][ni], 0, 0, 0);
  }
  const int c0 = (lane >> 4) << 2;
  if (w >= 4) {
#pragma unroll
    for (int mi = 0; mi < 3; ++mi)
#pragma unroll
      for (int ni = 0; ni < 3; ++ni)
#pragma unroll
        for (int r = 0; r < 4; ++r)
          Sred[w - 4][mi * 16 + c0 + r][ni * 16 + row] = acc[mi][ni][r];
  }
  __syncthreads();
  if (w < 4) {
#pragma unroll
    for (int mi = 0; mi < 3; ++mi)
#pragma unroll
      for (int ni = 0; ni < 3; ++ni)
#pragma unroll
        for (int r = 0; r < 4; ++r)
          Sred[w][mi * 16 + c0 + r][ni * 16 + row] += acc[mi][ni][r];
  }
  __syncthreads();
  if (tid < 48) {
    float sq = 0.f, skk = 0.f;
#pragma unroll
    for (int s = 0; s < 8; ++s) {
      sq  += partial[((size_t)b * 1152 + h * CHD + tid) * 8 + s];
      skk += partial[((size_t)b * 1152 + DIMC + h * CHD + tid) * 8 + s];
    }
    invq[tid] = 1.f / fmaxf(sqrtf(sq), 1e-12f);
    invk[tid] = 1.f / fmaxf(sqrtf(skk), 1e-12f);
  }
  __syncthreads();
  if (tid < 48) {
    float tp = temp[h];
    float vq = invq[tid] * tp;
    float vals[48];
    float mx = -1e30f;
#pragma unroll
    for (int d = 0; d < 48; ++d) {
      float s = Sred[0][tid][d] + Sred[1][tid][d] + Sred[2][tid][d] + Sred[3][tid][d];
      s *= vq * invk[d];
      vals[d] = s;
      mx = fmaxf(mx, s);
    }
    float sum = 0.f;
#pragma unroll
    for (int d = 0; d < 48; ++d) { vals[d] = expf(vals[d] - mx); sum += vals[d]; }
    float inv = 1.f / sum;
    float* Arow = Aat + ((size_t)(b * 8 + h) * 48 + tid) * 48;
#pragma unroll
    for (int d = 0; d < 48; ++d) Arow[d] = vals[d] * inv;
  }
}

// M[b][o][h*48+d] = sum_c wproj[o][h*48+c] * A[b][h*48+c][d], bf16 out.
__global__ __launch_bounds__(256) void k_combine(
    const float* __restrict__ wproj, const float* __restrict__ Aat,
    unsigned short* __restrict__ M)
{
  int idx = blockIdx.x * 256 + threadIdx.x;      // over 8*384*384
  int b = idx / WELEM;
  int r2 = idx - b * WELEM;
  int o = r2 / DIMC;
  int dg = r2 - o * DIMC;
  int h = dg / CHD, d = dg - h * CHD;
  const float* wrow = wproj + (size_t)o * DIMC + h * CHD;
  const float* Acol = Aat + (size_t)b * DIMC * CHD + (size_t)(h * CHD) * CHD + d;
  float s = 0.f;
#pragma unroll
  for (int c = 0; c < CHD; ++c)
    s = fmaf(wrow[c], Acol[c * CHD], s);
  M[idx] = f2bf(s);
}

extern "C" void kernel_launch(void* const* d_in, const int* in_sizes, int n_in,
                              void* d_out, int out_size, void* d_ws, size_t ws_size,
                              hipStream_t stream)
{
  const float* x     = (const float*)d_in[0];
  const float* w0    = (const float*)d_in[1];
  const float* w1    = (const float*)d_in[2];
  const float* w2    = (const float*)d_in[3];
  const float* dw0   = (const float*)d_in[4];
  const float* dw1   = (const float*)d_in[5];
  const float* dw2   = (const float*)d_in[6];
  const float* wproj = (const float*)d_in[7];
  const float* temp  = (const float*)d_in[8];
  float* out = (float*)d_out;

  // ws layout (709 MB of 768 MiB). vT aliases XT (XT dead after conv_mfma).
  char* p = (char*)d_ws;
  unsigned short* Wc     = (unsigned short*)p;  p += (size_t)3 * WELEM * 2;            // 884,736
  unsigned short* XT     = (unsigned short*)p;  p += (size_t)NB * PERT * 2;            // 100.7 MB
  unsigned short* q0k0v0 = (unsigned short*)p;  p += (size_t)NB * 3 * PERT * 2;        // 302 MB
  unsigned short* qkv    = (unsigned short*)p;  p += (size_t)NB * 3 * PERT * 2;        // 302 MB
  float* Aat     = (float*)p;  p += (size_t)NB * DIMC * CHD * 4;                       // 590 KB
  float* partial = (float*)p;  p += (size_t)NB * 3 * DIMC * 8 * 4;                     // 295 KB
  unsigned short* Mbf = (unsigned short*)p;                                            // 2.36 MB
  unsigned short* vT = XT;   // alias

  k_convert_w<<<(3 * WELEM + 255) / 256, 256, 0, stream>>>(w0, w1, w2, Wc);
  k_transpose_x<<<dim3(256, 6, NB), 256, 0, stream>>>(x, XT);
  k_conv_mfma<<<dim3(9, 128, NB), 256, 0, stream>>>(Wc, XT, q0k0v0);
  k_dwconv<<<NB * 3 * DIMC * 8, 256, 0, stream>>>(q0k0v0, dw0, dw1, dw2, qkv, partial);
  k_transpose_v<<<dim3(256, 6, NB), 256, 0, stream>>>(qkv, vT);
  k_attn<<<NB * NHEADS, 512, 0, stream>>>(qkv, partial, temp, Aat);
  k_combine<<<(NB * WELEM) / 256, 256, 0, stream>>>(wproj, Aat, Mbf);
  k_final_mfma<<<dim3(3, 128, NB), 256, 0, stream>>>(Mbf, vT, out);
  (void)in_sizes; (void)n_in; (void)out_size; (void)ws_size;
}

// Round 5
// 733.836 us; speedup vs baseline: 7.0145x; 1.1423x over previous
//
#include <hip/hip_runtime.h>
#include <math.h>

#define DIMC 384
#define NHEADS 8
#define CHD 48
#define HWN 16384
#define IMW 128
#define PERT ((size_t)DIMC * HWN)   // elements per [384,128,128] tensor
#define WELEM (DIMC * DIMC)         // 147456
#define NB 8

typedef short short8 __attribute__((ext_vector_type(8)));
typedef unsigned short u16x8 __attribute__((ext_vector_type(8)));
typedef float f32x4 __attribute__((ext_vector_type(4)));

__device__ __forceinline__ unsigned short f2bf(float f) {
  unsigned int u = __float_as_uint(f);
  unsigned int r = (u + 0x7fffu + ((u >> 16) & 1u)) >> 16;   // RNE
  return (unsigned short)r;
}
__device__ __forceinline__ float bf2f(unsigned short b) {
  return __uint_as_float(((unsigned int)b) << 16);
}
__device__ __forceinline__ void async16(const void* g, void* l) {
  __builtin_amdgcn_global_load_lds(
      (const __attribute__((address_space(1))) void*)g,
      (__attribute__((address_space(3))) void*)l, 16, 0, 0);
}

// ---------------------------------------------------------------------------
// bf16 MFMA GEMM, 2-phase pipelined (T3-minimum): Y[128m x 128n] = A @ B.
// A storage and BT storage are both pre-XOR-swizzled per 128B k-chunk:
// element (r,k) stored at (k&~63) | ((k&63) ^ ((r&7)<<3)). Stage copies rows
// linearly via global_load_lds (linear LDS dest); ds_read applies the XOR.
// Double-buffered A+B LDS (64KB). One barrier per K-step; stage(t+1) issued
// before compute(t) so load latency hides under 32 MFMAs.
// ---------------------------------------------------------------------------
template <int OUTBF>
__device__ __forceinline__ void mfma_gemm(
    const unsigned short* __restrict__ A,
    const unsigned short* __restrict__ BT,
    void* __restrict__ Y, int obase, int nbase)
{
  __shared__ unsigned short As[2][8192];   // 2 x 16 KB
  __shared__ unsigned short Bs[2][8192];
  const int tid = threadIdx.x;
  const int lane = tid & 63;
  const int wv = tid >> 6;
  const int wm = (wv >> 1) * 64;
  const int wn = (wv & 1) * 64;

  f32x4 acc[4][4];
#pragma unroll
  for (int i = 0; i < 4; ++i)
#pragma unroll
    for (int j = 0; j < 4; ++j) acc[i][j] = (f32x4){0.f, 0.f, 0.f, 0.f};

  const int srow = tid >> 3;           // 0..31
  const int sks = (tid & 7) * 8;       // shorts within 64-elem chunk
  const unsigned short* asrc = A + (size_t)(obase + srow) * DIMC + sks;
  const unsigned short* bsrc = BT + (size_t)(nbase + srow) * DIMC + sks;

  const int ar = wm + (lane & 15);
  const int br = wn + (lane & 15);
  const int kg = (lane >> 4) << 4;     // byte offset base within 128B chunk
  const int sw = (lane & 7) << 4;      // row-XOR swizzle (row&7 == lane&7)

#define STAGE(buf, k0)                                                   \
  do {                                                                   \
    _Pragma("unroll") for (int i = 0; i < 4; ++i)                        \
        async16(asrc + (size_t)(i * 32) * DIMC + (k0),                   \
                &As[buf][(tid + i * 256) * 8]);                          \
    _Pragma("unroll") for (int i = 0; i < 4; ++i)                        \
        async16(bsrc + (size_t)(i * 32) * DIMC + (k0),                   \
                &Bs[buf][(tid + i * 256) * 8]);                          \
  } while (0)

  STAGE(0, 0);
  __syncthreads();

#pragma unroll
  for (int t = 0; t < 6; ++t) {
    const int cur = t & 1;
    if (t < 5) STAGE(cur ^ 1, (t + 1) * 64);   // prefetch next K-tile
#pragma unroll
    for (int kq = 0; kq < 2; ++kq) {
      const int kb = kq * 64 + kg;
      short8 af[4], bf[4];
#pragma unroll
      for (int mi = 0; mi < 4; ++mi)
        af[mi] = *reinterpret_cast<const short8*>(
            (const char*)&As[cur][0] + (ar + mi * 16) * 128 + (kb ^ sw));
#pragma unroll
      for (int ni = 0; ni < 4; ++ni)
        bf[ni] = *reinterpret_cast<const short8*>(
            (const char*)&Bs[cur][0] + (br + ni * 16) * 128 + (kb ^ sw));
#pragma unroll
      for (int mi = 0; mi < 4; ++mi)
#pragma unroll
        for (int ni = 0; ni < 4; ++ni)
          acc[mi][ni] = __builtin_amdgcn_mfma_f32_16x16x32_bf16(
              af[mi], bf[ni], acc[mi][ni], 0, 0, 0);
    }
    if (t < 5) __syncthreads();   // drains vmcnt(0): stage(t+1) complete
  }
#undef STAGE

  const int orow = obase + wm + ((lane >> 4) << 2);
  const int ocol = nbase + wn + (lane & 15);
#pragma unroll
  for (int mi = 0; mi < 4; ++mi)
#pragma unroll
    for (int ni = 0; ni < 4; ++ni)
#pragma unroll
      for (int r = 0; r < 4; ++r) {
        size_t off = (size_t)(orow + mi * 16 + r) * HWN + ocol + ni * 16;
        if (OUTBF) ((unsigned short*)Y)[off] = f2bf(acc[mi][ni][r]);
        else       ((float*)Y)[off] = acc[mi][ni][r];
      }
}

// q0k0v0[b] = {w0,w1,w2} @ x[b]. grid (9,128,8). XCD swizzle over 9216 blocks.
__global__ __launch_bounds__(256) void k_conv_mfma(
    const unsigned short* __restrict__ Wc, const unsigned short* __restrict__ XT,
    unsigned short* __restrict__ Y)
{
  int lin = ((int)blockIdx.z * 128 + blockIdx.y) * 9 + blockIdx.x;  // 0..9215
  int swz = (lin & 7) * 1152 + (lin >> 3);
  int g = swz / 9, r = swz - g * 9;      // g = b*128 + nt
  int bb = g >> 7, nt = g & 127;
  int j = r / 3, mt = r - j * 3;
  mfma_gemm<1>(Wc + j * WELEM, XT + (size_t)bb * PERT,
               Y + (size_t)bb * 3 * PERT + (size_t)j * PERT, mt * 128, nt * 128);
}

// out[b] = M[b] @ v[b]. grid (3,128,8).
__global__ __launch_bounds__(256) void k_final_mfma(
    const unsigned short* __restrict__ M, const unsigned short* __restrict__ vT,
    float* __restrict__ out)
{
  int lin = ((int)blockIdx.z * 128 + blockIdx.y) * 3 + blockIdx.x;  // 0..3071
  int swz = (lin & 7) * 384 + (lin >> 3);
  int g = swz / 3, mt = swz - g * 3;
  int bb = g >> 7, nt = g & 127;
  mfma_gemm<0>(M + (size_t)bb * WELEM, vT + (size_t)bb * PERT,
               out + (size_t)bb * PERT, mt * 128, nt * 128);
}

// transpose+convert x[b][c][n] f32 -> XT[b][n][c] bf16, rows XOR-swizzled.
__global__ __launch_bounds__(256) void k_transpose_x(
    const float* __restrict__ x, unsigned short* __restrict__ XT)
{
  __shared__ unsigned short S[64][72];
  int n0 = blockIdx.x * 64, c0 = blockIdx.y * 64;
  const float* xb = x + (size_t)blockIdx.z * PERT;
  unsigned short* XTb = XT + (size_t)blockIdx.z * PERT;
  int t = threadIdx.x;
  int cl = t >> 2, ns = (t & 3) * 16;
  const float* src = &xb[(size_t)(c0 + cl) * HWN + n0 + ns];
#pragma unroll
  for (int i = 0; i < 16; i += 4) {
    float4 v = *reinterpret_cast<const float4*>(&src[i]);
    S[cl][ns + i + 0] = f2bf(v.x);
    S[cl][ns + i + 1] = f2bf(v.y);
    S[cl][ns + i + 2] = f2bf(v.z);
    S[cl][ns + i + 3] = f2bf(v.w);
  }
  __syncthreads();
  int nl = t >> 2, cs = (t & 3) * 16;
  unsigned short tmp[16];
#pragma unroll
  for (int i = 0; i < 16; ++i) tmp[i] = S[cs + i][nl];
  u16x8 p0, p1;
#pragma unroll
  for (int i = 0; i < 8; ++i) { p0[i] = tmp[i]; p1[i] = tmp[8 + i]; }
  char* rowb = (char*)XTb + (size_t)(n0 + nl) * (DIMC * 2);
  int cb = (c0 + cs) * 2;
  int sw = (nl & 7) << 4;
  *reinterpret_cast<u16x8*>(rowb + ((cb) ^ sw)) = p0;
  *reinterpret_cast<u16x8*>(rowb + ((cb + 16) ^ sw)) = p1;
}

// transpose v[b][c][n] bf16 -> vT[b][n][c] bf16, same swizzle.
__global__ __launch_bounds__(256) void k_transpose_v(
    const unsigned short* __restrict__ qkv, unsigned short* __restrict__ vT)
{
  __shared__ unsigned short S[64][72];
  int n0 = blockIdx.x * 64, c0 = blockIdx.y * 64;
  const unsigned short* v = qkv + (size_t)blockIdx.z * 3 * PERT + 2 * PERT;
  unsigned short* vTb = vT + (size_t)blockIdx.z * PERT;
  int t = threadIdx.x;
  int cl = t >> 2, ns = (t & 3) * 16;
  const unsigned short* src = &v[(size_t)(c0 + cl) * HWN + n0 + ns];
  *reinterpret_cast<u16x8*>(&S[cl][ns]) = *reinterpret_cast<const u16x8*>(&src[0]);
  *reinterpret_cast<u16x8*>(&S[cl][ns + 8]) = *reinterpret_cast<const u16x8*>(&src[8]);
  __syncthreads();
  int nl = t >> 2, cs = (t & 3) * 16;
  unsigned short tmp[16];
#pragma unroll
  for (int i = 0; i < 16; ++i) tmp[i] = S[cs + i][nl];
  u16x8 p0, p1;
#pragma unroll
  for (int i = 0; i < 8; ++i) { p0[i] = tmp[i]; p1[i] = tmp[8 + i]; }
  char* rowb = (char*)vTb + (size_t)(n0 + nl) * (DIMC * 2);
  int cb = (c0 + cs) * 2;
  int sw = (nl & 7) << 4;
  *reinterpret_cast<u16x8*>(rowb + ((cb) ^ sw)) = p0;
  *reinterpret_cast<u16x8*>(rowb + ((cb + 16) ^ sw)) = p1;
}

// w -> bf16, stored XOR-swizzled per 64-elem k-chunk (A-operand layout).
__global__ __launch_bounds__(256) void k_convert_w(
    const float* __restrict__ w0, const float* __restrict__ w1,
    const float* __restrict__ w2, unsigned short* __restrict__ Wc)
{
  int idx = blockIdx.x * 256 + threadIdx.x;      // < 3*147456
  int j = idx / WELEM, r = idx - j * WELEM;
  int m = r / DIMC, k = r - m * DIMC;
  const float* s = (j == 0) ? w0 : (j == 1) ? w1 : w2;
  int kd = (k & ~63) | ((k & 63) ^ ((m & 7) << 3));
  Wc[j * WELEM + m * DIMC + kd] = f2bf(s[r]);
}

// depthwise 3x3 SAME, bf16 in/out, 8 px per thread; per-block sum-of-squares
// partial (8 blocks per plane). planes: [b][j][c], 9216 total.
__global__ __launch_bounds__(256) void k_dwconv(
    const unsigned short* __restrict__ Yin, const float* __restrict__ dw0,
    const float* __restrict__ dw1, const float* __restrict__ dw2,
    unsigned short* __restrict__ Zout, float* __restrict__ partial)
{
  __shared__ float red[4];
  int gid = blockIdx.x * 256 + threadIdx.x;
  int plane = gid >> 11;                 // 2048 8px-units per plane
  int rem = gid & 2047;
  int pl = plane % (3 * DIMC);
  int j = pl / DIMC;
  int c = pl - j * DIMC;
  int h = rem >> 4;
  int w0p = (rem & 15) << 3;
  const float* dw = ((j == 0) ? dw0 : (j == 1) ? dw1 : dw2) + c * 9;
  const unsigned short* src = Yin + (size_t)plane * HWN;
  float a[8] = {0.f, 0.f, 0.f, 0.f, 0.f, 0.f, 0.f, 0.f};
#pragma unroll
  for (int dy = -1; dy <= 1; ++dy) {
    int hh = h + dy;
    if (hh < 0 || hh >= IMW) continue;
    const unsigned short* row = src + hh * IMW;
    u16x8 m = *reinterpret_cast<const u16x8*>(&row[w0p]);
    float mf[8];
#pragma unroll
    for (int i = 0; i < 8; ++i) mf[i] = bf2f(m[i]);
    float lf = (w0p > 0) ? bf2f(row[w0p - 1]) : 0.f;
    float rf = (w0p < 120) ? bf2f(row[w0p + 8]) : 0.f;
    float t0 = dw[(dy + 1) * 3], t1 = dw[(dy + 1) * 3 + 1], t2 = dw[(dy + 1) * 3 + 2];
    a[0] += lf * t0 + mf[0] * t1 + mf[1] * t2;
#pragma unroll
    for (int i = 1; i < 7; ++i)
      a[i] += mf[i - 1] * t0 + mf[i] * t1 + mf[i + 1] * t2;
    a[7] += mf[6] * t0 + mf[7] * t1 + rf * t2;
  }
  u16x8 o;
#pragma unroll
  for (int i = 0; i < 8; ++i) o[i] = f2bf(a[i]);
  *reinterpret_cast<u16x8*>(&Zout[(size_t)plane * HWN + h * IMW + w0p]) = o;
  if (j < 2) {
    float s = 0.f;
#pragma unroll
    for (int i = 0; i < 8; ++i) s += a[i] * a[i];
#pragma unroll
    for (int off = 32; off > 0; off >>= 1) s += __shfl_down(s, off);
    if ((threadIdx.x & 63) == 0) red[threadIdx.x >> 6] = s;
    __syncthreads();
    if (threadIdx.x == 0)
      partial[blockIdx.x] = red[0] + red[1] + red[2] + red[3];
  }
}

// q@k^T partials: grid 512 = (b, h, slice of 2048 px). 4 waves x 512 px.
// 48x48 MFMA accum straight from global (k-contiguous), cross-wave LDS
// reduce, write Spart[blk][48*48]. No atomics.
__global__ __launch_bounds__(256) void k_qk_mfma(
    const unsigned short* __restrict__ qkv, float* __restrict__ Spart)
{
  __shared__ float Sred[4][2304];
  int blk = blockIdx.x;
  int b = blk >> 6, h = (blk >> 3) & 7, slice = blk & 7;
  int tid = threadIdx.x, lane = tid & 63, w = tid >> 6;
  const unsigned short* qb = qkv + ((size_t)b * 3 * DIMC + h * CHD) * HWN;
  const unsigned short* kb = qb + (size_t)DIMC * HWN;
  const int row = lane & 15;
  const int ko = (lane >> 4) << 3;
  const int n0 = slice * 2048 + w * 512;

  f32x4 acc[3][3];
#pragma unroll
  for (int i = 0; i < 3; ++i)
#pragma unroll
    for (int j = 0; j < 3; ++j) acc[i][j] = (f32x4){0.f, 0.f, 0.f, 0.f};

  for (int ns = n0; ns < n0 + 512; ns += 32) {
    short8 aq[3], bk[3];
#pragma unroll
    for (int mi = 0; mi < 3; ++mi)
      aq[mi] = *reinterpret_cast<const short8*>(&qb[(size_t)(mi * 16 + row) * HWN + ns + ko]);
#pragma unroll
    for (int ni = 0; ni < 3; ++ni)
      bk[ni] = *reinterpret_cast<const short8*>(&kb[(size_t)(ni * 16 + row) * HWN + ns + ko]);
#pragma unroll
    for (int mi = 0; mi < 3; ++mi)
#pragma unroll
      for (int ni = 0; ni < 3; ++ni)
        acc[mi][ni] = __builtin_amdgcn_mfma_f32_16x16x32_bf16(
            aq[mi], bk[ni], acc[mi][ni], 0, 0, 0);
  }
  const int c0 = (lane >> 4) << 2;
#pragma unroll
  for (int mi = 0; mi < 3; ++mi)
#pragma unroll
    for (int ni = 0; ni < 3; ++ni)
#pragma unroll
      for (int r = 0; r < 3 + 1; ++r)
        Sred[w][(mi * 16 + c0 + r) * 48 + ni * 16 + row] = acc[mi][ni][r];
  __syncthreads();
  float* dst = Spart + (size_t)blk * 2304;
#pragma unroll
  for (int i = 0; i < 9; ++i) {
    int e = tid + i * 256;
    dst[e] = Sred[0][e] + Sred[1][e] + Sred[2][e] + Sred[3][e];
  }
}

// slice-sum + L2-norm scale + softmax. grid = 8 (per b), 384 thr = row (h,c).
__global__ __launch_bounds__(384) void k_attn_sm(
    const float* __restrict__ Spart, const float* __restrict__ partial,
    const float* __restrict__ temp, float* __restrict__ Aat)
{
  __shared__ float sk[DIMC];
  int b = blockIdx.x, t = threadIdx.x;
  int h = t / CHD, c = t - h * CHD;
  float sq = 0.f, skk = 0.f;
#pragma unroll
  for (int s = 0; s < 8; ++s) {
    sq  += partial[((size_t)b * 1152 + t) * 8 + s];
    skk += partial[((size_t)b * 1152 + DIMC + t) * 8 + s];
  }
  sk[t] = 1.f / fmaxf(sqrtf(skk), 1e-12f);
  float invq = 1.f / fmaxf(sqrtf(sq), 1e-12f);
  __syncthreads();
  float vals[CHD];
#pragma unroll
  for (int d = 0; d < CHD; ++d) vals[d] = 0.f;
  for (int sl = 0; sl < 8; ++sl) {
    const float* sp = Spart + (size_t)(b * 64 + h * 8 + sl) * 2304 + c * 48;
#pragma unroll
    for (int d = 0; d < CHD; ++d) vals[d] += sp[d];
  }
  float tp = temp[h];
  float vq = invq * tp;
  float mx = -1e30f;
#pragma unroll
  for (int d = 0; d < CHD; ++d) {
    vals[d] *= vq * sk[h * CHD + d];
    mx = fmaxf(mx, vals[d]);
  }
  float sum = 0.f;
#pragma unroll
  for (int d = 0; d < CHD; ++d) { vals[d] = expf(vals[d] - mx); sum += vals[d]; }
  float inv = 1.f / sum;
  float* Arow = Aat + ((size_t)(b * 8 + h) * 48 + c) * 48;
#pragma unroll
  for (int d = 0; d < CHD; ++d) Arow[d] = vals[d] * inv;
}

// M[b][o][h*48+d] = sum_c wproj[o][h*48+c] * A[b][h*48+c][d], bf16 out,
// stored XOR-swizzled (A-operand layout for k_final_mfma).
__global__ __launch_bounds__(256) void k_combine(
    const float* __restrict__ wproj, const float* __restrict__ Aat,
    unsigned short* __restrict__ M)
{
  int idx = blockIdx.x * 256 + threadIdx.x;      // over 8*384*384
  int b = idx / WELEM;
  int r2 = idx - b * WELEM;
  int o = r2 / DIMC;
  int dg = r2 - o * DIMC;
  int h = dg / CHD, d = dg - h * CHD;
  const float* wrow = wproj + (size_t)o * DIMC + h * CHD;
  const float* Acol = Aat + (size_t)b * DIMC * CHD + (size_t)(h * CHD) * CHD + d;
  float s = 0.f;
#pragma unroll
  for (int c = 0; c < CHD; ++c)
    s = fmaf(wrow[c], Acol[c * CHD], s);
  int dd = (dg & ~63) | ((dg & 63) ^ ((o & 7) << 3));
  M[b * WELEM + o * DIMC + dd] = f2bf(s);
}

extern "C" void kernel_launch(void* const* d_in, const int* in_sizes, int n_in,
                              void* d_out, int out_size, void* d_ws, size_t ws_size,
                              hipStream_t stream)
{
  const float* x     = (const float*)d_in[0];
  const float* w0    = (const float*)d_in[1];
  const float* w1    = (const float*)d_in[2];
  const float* w2    = (const float*)d_in[3];
  const float* dw0   = (const float*)d_in[4];
  const float* dw1   = (const float*)d_in[5];
  const float* dw2   = (const float*)d_in[6];
  const float* wproj = (const float*)d_in[7];
  const float* temp  = (const float*)d_in[8];
  float* out = (float*)d_out;

  // ws layout. vT aliases XT (XT dead after conv_mfma).
  char* p = (char*)d_ws;
  unsigned short* Wc     = (unsigned short*)p;  p += (size_t)3 * WELEM * 2;            // 884,736
  unsigned short* XT     = (unsigned short*)p;  p += (size_t)NB * PERT * 2;            // 100.7 MB
  unsigned short* q0k0v0 = (unsigned short*)p;  p += (size_t)NB * 3 * PERT * 2;        // 302 MB
  unsigned short* qkv    = (unsigned short*)p;  p += (size_t)NB * 3 * PERT * 2;        // 302 MB
  float* Spart   = (float*)p;  p += (size_t)512 * 2304 * 4;                            // 4.7 MB
  float* Aat     = (float*)p;  p += (size_t)NB * DIMC * CHD * 4;                       // 590 KB
  float* partial = (float*)p;  p += (size_t)NB * 3 * DIMC * 8 * 4;                     // 295 KB
  unsigned short* Mbf = (unsigned short*)p;                                            // 2.36 MB
  unsigned short* vT = XT;   // alias

  k_convert_w<<<(3 * WELEM + 255) / 256, 256, 0, stream>>>(w0, w1, w2, Wc);
  k_transpose_x<<<dim3(256, 6, NB), 256, 0, stream>>>(x, XT);
  k_conv_mfma<<<dim3(9, 128, NB), 256, 0, stream>>>(Wc, XT, q0k0v0);
  k_dwconv<<<NB * 3 * DIMC * 8, 256, 0, stream>>>(q0k0v0, dw0, dw1, dw2, qkv, partial);
  k_transpose_v<<<dim3(256, 6, NB), 256, 0, stream>>>(qkv, vT);
  k_qk_mfma<<<512, 256, 0, stream>>>(qkv, Spart);
  k_attn_sm<<<NB, 384, 0, stream>>>(Spart, partial, temp, Aat);
  k_combine<<<(NB * WELEM) / 256, 256, 0, stream>>>(wproj, Aat, Mbf);
  k_final_mfma<<<dim3(3, 128, NB), 256, 0, stream>>>(Mbf, vT, out);
  (void)in_sizes; (void)n_in; (void)out_size; (void)ws_size;
}

// Round 6
// 726.045 us; speedup vs baseline: 7.0898x; 1.0107x over previous
//
#include <hip/hip_runtime.h>
#include <math.h>

#define DIMC 384
#define NHEADS 8
#define CHD 48
#define HWN 16384
#define IMW 128
#define PERT ((size_t)DIMC * HWN)   // elements per [384,128,128] tensor
#define WELEM (DIMC * DIMC)         // 147456
#define NB 8

typedef short short8 __attribute__((ext_vector_type(8)));
typedef unsigned short u16x8 __attribute__((ext_vector_type(8)));
typedef float f32x4 __attribute__((ext_vector_type(4)));

__device__ __forceinline__ unsigned short f2bf(float f) {
  unsigned int u = __float_as_uint(f);
  unsigned int r = (u + 0x7fffu + ((u >> 16) & 1u)) >> 16;   // RNE
  return (unsigned short)r;
}
__device__ __forceinline__ float bf2f(unsigned short b) {
  return __uint_as_float(((unsigned int)b) << 16);
}
__device__ __forceinline__ void async16(const void* g, void* l) {
  __builtin_amdgcn_global_load_lds(
      (const __attribute__((address_space(1))) void*)g,
      (__attribute__((address_space(3))) void*)l, 16, 0, 0);
}

// ---------------------------------------------------------------------------
// bf16 MFMA GEMM, 3-deep counted-vmcnt pipeline (T3/T4/T5).
// Tile: BM=128 x BN=256, BK=64, 512 threads (8 waves, 2Mx4N, 64x64/wave).
// A and BT global storage pre-XOR-swizzled per 128B k-chunk:
//   element (r,k) at (k&~63) | ((k&63) ^ ((r&7)<<3)).
// Stage = linear global_load_lds copies (6/thread); ds_read applies the XOR.
// 3 LDS buffers (144 KB -> 1 block/CU, 8 waves). Steady state: 18 loads
// outstanding, s_waitcnt vmcnt(12) before each raw s_barrier (never 0 in
// loop). setprio(1) around MFMA cluster.
// ---------------------------------------------------------------------------
template <int OUTBF>
__device__ __forceinline__ void mfma_gemm(
    const unsigned short* __restrict__ A,
    const unsigned short* __restrict__ BT,
    void* __restrict__ Y, int obase, int nbase)
{
  __shared__ unsigned short As[3][8192];    // 3 x 16 KB (128 rows x 128B)
  __shared__ unsigned short Bs[3][16384];   // 3 x 32 KB (256 rows x 128B)
  const int tid = threadIdx.x;
  const int lane = tid & 63;
  const int wv = tid >> 6;              // 0..7
  const int wm = (wv >> 2) * 64;
  const int wn = (wv & 3) * 64;

  f32x4 acc[4][4];
#pragma unroll
  for (int i = 0; i < 4; ++i)
#pragma unroll
    for (int j = 0; j < 4; ++j) acc[i][j] = (f32x4){0.f, 0.f, 0.f, 0.f};

  const int srow = tid >> 3;            // 0..63
  const int sks = (tid & 7) * 8;        // shorts within 64-elem chunk
  const unsigned short* asrc = A + (size_t)(obase + srow) * DIMC + sks;
  const unsigned short* bsrc = BT + (size_t)(nbase + srow) * DIMC + sks;

  const int ar = wm + (lane & 15);
  const int br = wn + (lane & 15);
  const int kg = (lane >> 4) << 4;      // byte offset base within 128B chunk
  const int sw = (lane & 7) << 4;       // row-XOR swizzle

#define WAITVM(n) asm volatile("s_waitcnt vmcnt(" #n ")" ::: "memory")
#define SBAR()                                 \
  do {                                         \
    __builtin_amdgcn_sched_barrier(0);         \
    __builtin_amdgcn_s_barrier();              \
    __builtin_amdgcn_sched_barrier(0);         \
  } while (0)

#define STAGE(buf, k0)                                                   \
  do {                                                                   \
    _Pragma("unroll") for (int i = 0; i < 2; ++i)                        \
        async16(asrc + (size_t)(i * 64) * DIMC + (k0),                   \
                &As[buf][(size_t)(tid + i * 512) * 8]);                  \
    _Pragma("unroll") for (int i = 0; i < 4; ++i)                        \
        async16(bsrc + (size_t)(i * 64) * DIMC + (k0),                   \
                &Bs[buf][(size_t)(tid + i * 512) * 8]);                  \
  } while (0)

#define COMPUTE(buf)                                                     \
  do {                                                                   \
    short8 af[2][4], bf[2][4];                                           \
    _Pragma("unroll") for (int kq = 0; kq < 2; ++kq) {                   \
      const int kb = kq * 64 + kg;                                       \
      _Pragma("unroll") for (int mi = 0; mi < 4; ++mi)                   \
          af[kq][mi] = *reinterpret_cast<const short8*>(                 \
              (const char*)&As[buf][0] + (ar + mi * 16) * 128 + (kb ^ sw)); \
      _Pragma("unroll") for (int ni = 0; ni < 4; ++ni)                   \
          bf[kq][ni] = *reinterpret_cast<const short8*>(                 \
              (const char*)&Bs[buf][0] + (br + ni * 16) * 128 + (kb ^ sw)); \
    }                                                                    \
    __builtin_amdgcn_s_setprio(1);                                       \
    _Pragma("unroll") for (int kq = 0; kq < 2; ++kq)                     \
      _Pragma("unroll") for (int mi = 0; mi < 4; ++mi)                   \
        _Pragma("unroll") for (int ni = 0; ni < 4; ++ni)                 \
          acc[mi][ni] = __builtin_amdgcn_mfma_f32_16x16x32_bf16(         \
              af[kq][mi], bf[ni ? ni : 0][ni], acc[mi][ni], 0, 0, 0);    \
    __builtin_amdgcn_s_setprio(0);                                       \
  } while (0)

  // NOTE: bf[kq][ni] (macro above writes bf[ni?ni:0][ni] — fix inline below)
#undef COMPUTE
#define COMPUTE(buf)                                                     \
  do {                                                                   \
    short8 af[2][4], bf[2][4];                                           \
    _Pragma("unroll") for (int kq = 0; kq < 2; ++kq) {                   \
      const int kb = kq * 64 + kg;                                       \
      _Pragma("unroll") for (int mi = 0; mi < 4; ++mi)                   \
          af[kq][mi] = *reinterpret_cast<const short8*>(                 \
              (const char*)&As[buf][0] + (ar + mi * 16) * 128 + (kb ^ sw)); \
      _Pragma("unroll") for (int ni = 0; ni < 4; ++ni)                   \
          bf[kq][ni] = *reinterpret_cast<const short8*>(                 \
              (const char*)&Bs[buf][0] + (br + ni * 16) * 128 + (kb ^ sw)); \
    }                                                                    \
    __builtin_amdgcn_s_setprio(1);                                       \
    _Pragma("unroll") for (int kq = 0; kq < 2; ++kq)                     \
      _Pragma("unroll") for (int mi = 0; mi < 4; ++mi)                   \
        _Pragma("unroll") for (int ni = 0; ni < 4; ++ni)                 \
          acc[mi][ni] = __builtin_amdgcn_mfma_f32_16x16x32_bf16(         \
              af[kq][mi], bf[kq][ni], acc[mi][ni], 0, 0, 0);             \
    __builtin_amdgcn_s_setprio(0);                                       \
  } while (0)

  // prologue: 3 K-tiles in flight (18 loads/thread outstanding)
  STAGE(0, 0);
  STAGE(1, 64);
  STAGE(2, 128);

  WAITVM(12); SBAR(); COMPUTE(0); SBAR(); STAGE(0, 192);
  WAITVM(12); SBAR(); COMPUTE(1); SBAR(); STAGE(1, 256);
  WAITVM(12); SBAR(); COMPUTE(2); SBAR(); STAGE(2, 320);
  WAITVM(12); SBAR(); COMPUTE(0);
  WAITVM(6);  SBAR(); COMPUTE(1);
  WAITVM(0);  SBAR(); COMPUTE(2);

#undef STAGE
#undef COMPUTE
#undef WAITVM
#undef SBAR

  const int orow = obase + wm + ((lane >> 4) << 2);
  const int ocol = nbase + wn + (lane & 15);
#pragma unroll
  for (int mi = 0; mi < 4; ++mi)
#pragma unroll
    for (int ni = 0; ni < 4; ++ni)
#pragma unroll
      for (int r = 0; r < 4; ++r) {
        size_t off = (size_t)(orow + mi * 16 + r) * HWN + ocol + ni * 16;
        if (OUTBF) ((unsigned short*)Y)[off] = f2bf(acc[mi][ni][r]);
        else       ((float*)Y)[off] = acc[mi][ni][r];
      }
}

// q0k0v0[b] = {w0,w1,w2} @ x[b]. grid (9,64,8): 9 = 3 j x 3 mtile, 64 n-tiles.
// XCD swizzle keeps the 9 (j,mt) blocks of one n-tile adjacent on one XCD.
__global__ __launch_bounds__(512) void k_conv_mfma(
    const unsigned short* __restrict__ Wc, const unsigned short* __restrict__ XT,
    unsigned short* __restrict__ Y)
{
  int lin = ((int)blockIdx.z * 64 + blockIdx.y) * 9 + blockIdx.x;  // 0..4607
  int swz = (lin & 7) * 576 + (lin >> 3);
  int g = swz / 9, r = swz - g * 9;      // g = b*64 + nt
  int bb = g >> 6, nt = g & 63;
  int j = r / 3, mt = r - j * 3;
  mfma_gemm<1>(Wc + j * WELEM, XT + (size_t)bb * PERT,
               Y + (size_t)bb * 3 * PERT + (size_t)j * PERT, mt * 128, nt * 256);
}

// out[b] = M[b] @ v[b]. grid (3,64,8).
__global__ __launch_bounds__(512) void k_final_mfma(
    const unsigned short* __restrict__ M, const unsigned short* __restrict__ vT,
    float* __restrict__ out)
{
  int lin = ((int)blockIdx.z * 64 + blockIdx.y) * 3 + blockIdx.x;  // 0..1535
  int swz = (lin & 7) * 192 + (lin >> 3);
  int g = swz / 3, mt = swz - g * 3;
  int bb = g >> 6, nt = g & 63;
  mfma_gemm<0>(M + (size_t)bb * WELEM, vT + (size_t)bb * PERT,
               out + (size_t)bb * PERT, mt * 128, nt * 256);
}

// transpose+convert x[b][c][n] f32 -> XT[b][n][c] bf16, rows XOR-swizzled.
__global__ __launch_bounds__(256) void k_transpose_x(
    const float* __restrict__ x, unsigned short* __restrict__ XT)
{
  __shared__ unsigned short S[64][72];
  int n0 = blockIdx.x * 64, c0 = blockIdx.y * 64;
  const float* xb = x + (size_t)blockIdx.z * PERT;
  unsigned short* XTb = XT + (size_t)blockIdx.z * PERT;
  int t = threadIdx.x;
  int cl = t >> 2, ns = (t & 3) * 16;
  const float* src = &xb[(size_t)(c0 + cl) * HWN + n0 + ns];
#pragma unroll
  for (int i = 0; i < 16; i += 4) {
    float4 v = *reinterpret_cast<const float4*>(&src[i]);
    S[cl][ns + i + 0] = f2bf(v.x);
    S[cl][ns + i + 1] = f2bf(v.y);
    S[cl][ns + i + 2] = f2bf(v.z);
    S[cl][ns + i + 3] = f2bf(v.w);
  }
  __syncthreads();
  int nl = t >> 2, cs = (t & 3) * 16;
  unsigned short tmp[16];
#pragma unroll
  for (int i = 0; i < 16; ++i) tmp[i] = S[cs + i][nl];
  u16x8 p0, p1;
#pragma unroll
  for (int i = 0; i < 8; ++i) { p0[i] = tmp[i]; p1[i] = tmp[8 + i]; }
  char* rowb = (char*)XTb + (size_t)(n0 + nl) * (DIMC * 2);
  int cb = (c0 + cs) * 2;
  int sw = (nl & 7) << 4;
  *reinterpret_cast<u16x8*>(rowb + ((cb) ^ sw)) = p0;
  *reinterpret_cast<u16x8*>(rowb + ((cb + 16) ^ sw)) = p1;
}

// transpose v[b][c][n] bf16 -> vT[b][n][c] bf16, same swizzle.
__global__ __launch_bounds__(256) void k_transpose_v(
    const unsigned short* __restrict__ qkv, unsigned short* __restrict__ vT)
{
  __shared__ unsigned short S[64][72];
  int n0 = blockIdx.x * 64, c0 = blockIdx.y * 64;
  const unsigned short* v = qkv + (size_t)blockIdx.z * 3 * PERT + 2 * PERT;
  unsigned short* vTb = vT + (size_t)blockIdx.z * PERT;
  int t = threadIdx.x;
  int cl = t >> 2, ns = (t & 3) * 16;
  const unsigned short* src = &v[(size_t)(c0 + cl) * HWN + n0 + ns];
  *reinterpret_cast<u16x8*>(&S[cl][ns]) = *reinterpret_cast<const u16x8*>(&src[0]);
  *reinterpret_cast<u16x8*>(&S[cl][ns + 8]) = *reinterpret_cast<const u16x8*>(&src[8]);
  __syncthreads();
  int nl = t >> 2, cs = (t & 3) * 16;
  unsigned short tmp[16];
#pragma unroll
  for (int i = 0; i < 16; ++i) tmp[i] = S[cs + i][nl];
  u16x8 p0, p1;
#pragma unroll
  for (int i = 0; i < 8; ++i) { p0[i] = tmp[i]; p1[i] = tmp[8 + i]; }
  char* rowb = (char*)vTb + (size_t)(n0 + nl) * (DIMC * 2);
  int cb = (c0 + cs) * 2;
  int sw = (nl & 7) << 4;
  *reinterpret_cast<u16x8*>(rowb + ((cb) ^ sw)) = p0;
  *reinterpret_cast<u16x8*>(rowb + ((cb + 16) ^ sw)) = p1;
}

// w -> bf16, stored XOR-swizzled per 64-elem k-chunk (A-operand layout).
__global__ __launch_bounds__(256) void k_convert_w(
    const float* __restrict__ w0, const float* __restrict__ w1,
    const float* __restrict__ w2, unsigned short* __restrict__ Wc)
{
  int idx = blockIdx.x * 256 + threadIdx.x;      // < 3*147456
  int j = idx / WELEM, r = idx - j * WELEM;
  int m = r / DIMC, k = r - m * DIMC;
  const float* s = (j == 0) ? w0 : (j == 1) ? w1 : w2;
  int kd = (k & ~63) | ((k & 63) ^ ((m & 7) << 3));
  Wc[j * WELEM + m * DIMC + kd] = f2bf(s[r]);
}

// depthwise 3x3 SAME, bf16 in/out, 8 px per thread; per-block sum-of-squares
// partial (8 blocks per plane). planes: [b][j][c], 9216 total.
__global__ __launch_bounds__(256) void k_dwconv(
    const unsigned short* __restrict__ Yin, const float* __restrict__ dw0,
    const float* __restrict__ dw1, const float* __restrict__ dw2,
    unsigned short* __restrict__ Zout, float* __restrict__ partial)
{
  __shared__ float red[4];
  int gid = blockIdx.x * 256 + threadIdx.x;
  int plane = gid >> 11;                 // 2048 8px-units per plane
  int rem = gid & 2047;
  int pl = plane % (3 * DIMC);
  int j = pl / DIMC;
  int c = pl - j * DIMC;
  int h = rem >> 4;
  int w0p = (rem & 15) << 3;
  const float* dw = ((j == 0) ? dw0 : (j == 1) ? dw1 : dw2) + c * 9;
  const unsigned short* src = Yin + (size_t)plane * HWN;
  float a[8] = {0.f, 0.f, 0.f, 0.f, 0.f, 0.f, 0.f, 0.f};
#pragma unroll
  for (int dy = -1; dy <= 1; ++dy) {
    int hh = h + dy;
    if (hh < 0 || hh >= IMW) continue;
    const unsigned short* row = src + hh * IMW;
    u16x8 m = *reinterpret_cast<const u16x8*>(&row[w0p]);
    float mf[8];
#pragma unroll
    for (int i = 0; i < 8; ++i) mf[i] = bf2f(m[i]);
    float lf = (w0p > 0) ? bf2f(row[w0p - 1]) : 0.f;
    float rf = (w0p < 120) ? bf2f(row[w0p + 8]) : 0.f;
    float t0 = dw[(dy + 1) * 3], t1 = dw[(dy + 1) * 3 + 1], t2 = dw[(dy + 1) * 3 + 2];
    a[0] += lf * t0 + mf[0] * t1 + mf[1] * t2;
#pragma unroll
    for (int i = 1; i < 7; ++i)
      a[i] += mf[i - 1] * t0 + mf[i] * t1 + mf[i + 1] * t2;
    a[7] += mf[6] * t0 + mf[7] * t1 + rf * t2;
  }
  u16x8 o;
#pragma unroll
  for (int i = 0; i < 8; ++i) o[i] = f2bf(a[i]);
  *reinterpret_cast<u16x8*>(&Zout[(size_t)plane * HWN + h * IMW + w0p]) = o;
  if (j < 2) {
    float s = 0.f;
#pragma unroll
    for (int i = 0; i < 8; ++i) s += a[i] * a[i];
#pragma unroll
    for (int off = 32; off > 0; off >>= 1) s += __shfl_down(s, off);
    if ((threadIdx.x & 63) == 0) red[threadIdx.x >> 6] = s;
    __syncthreads();
    if (threadIdx.x == 0)
      partial[blockIdx.x] = red[0] + red[1] + red[2] + red[3];
  }
}

// q@k^T partials: grid 512 = (b, h, slice of 2048 px). 4 waves x 512 px.
__global__ __launch_bounds__(256) void k_qk_mfma(
    const unsigned short* __restrict__ qkv, float* __restrict__ Spart)
{
  __shared__ float Sred[4][2304];
  int blk = blockIdx.x;
  int b = blk >> 6, h = (blk >> 3) & 7, slice = blk & 7;
  int tid = threadIdx.x, lane = tid & 63, w = tid >> 6;
  const unsigned short* qb = qkv + ((size_t)b * 3 * DIMC + h * CHD) * HWN;
  const unsigned short* kb = qb + (size_t)DIMC * HWN;
  const int row = lane & 15;
  const int ko = (lane >> 4) << 3;
  const int n0 = slice * 2048 + w * 512;

  f32x4 acc[3][3];
#pragma unroll
  for (int i = 0; i < 3; ++i)
#pragma unroll
    for (int j = 0; j < 3; ++j) acc[i][j] = (f32x4){0.f, 0.f, 0.f, 0.f};

  for (int ns = n0; ns < n0 + 512; ns += 32) {
    short8 aq[3], bk[3];
#pragma unroll
    for (int mi = 0; mi < 3; ++mi)
      aq[mi] = *reinterpret_cast<const short8*>(&qb[(size_t)(mi * 16 + row) * HWN + ns + ko]);
#pragma unroll
    for (int ni = 0; ni < 3; ++ni)
      bk[ni] = *reinterpret_cast<const short8*>(&kb[(size_t)(ni * 16 + row) * HWN + ns + ko]);
#pragma unroll
    for (int mi = 0; mi < 3; ++mi)
#pragma unroll
      for (int ni = 0; ni < 3; ++ni)
        acc[mi][ni] = __builtin_amdgcn_mfma_f32_16x16x32_bf16(
            aq[mi], bk[ni], acc[mi][ni], 0, 0, 0);
  }
  const int c0 = (lane >> 4) << 2;
#pragma unroll
  for (int mi = 0; mi < 3; ++mi)
#pragma unroll
    for (int ni = 0; ni < 3; ++ni)
#pragma unroll
      for (int r = 0; r < 4; ++r)
        Sred[w][(mi * 16 + c0 + r) * 48 + ni * 16 + row] = acc[mi][ni][r];
  __syncthreads();
  float* dst = Spart + (size_t)blk * 2304;
#pragma unroll
  for (int i = 0; i < 9; ++i) {
    int e = tid + i * 256;
    dst[e] = Sred[0][e] + Sred[1][e] + Sred[2][e] + Sred[3][e];
  }
}

// slice-sum + L2-norm scale + softmax. grid = 8 (per b), 384 thr = row (h,c).
__global__ __launch_bounds__(384) void k_attn_sm(
    const float* __restrict__ Spart, const float* __restrict__ partial,
    const float* __restrict__ temp, float* __restrict__ Aat)
{
  __shared__ float sk[DIMC];
  int b = blockIdx.x, t = threadIdx.x;
  int h = t / CHD, c = t - h * CHD;
  float sq = 0.f, skk = 0.f;
#pragma unroll
  for (int s = 0; s < 8; ++s) {
    sq  += partial[((size_t)b * 1152 + t) * 8 + s];
    skk += partial[((size_t)b * 1152 + DIMC + t) * 8 + s];
  }
  sk[t] = 1.f / fmaxf(sqrtf(skk), 1e-12f);
  float invq = 1.f / fmaxf(sqrtf(sq), 1e-12f);
  __syncthreads();
  float vals[CHD];
#pragma unroll
  for (int d = 0; d < CHD; ++d) vals[d] = 0.f;
  for (int sl = 0; sl < 8; ++sl) {
    const float* sp = Spart + (size_t)(b * 64 + h * 8 + sl) * 2304 + c * 48;
#pragma unroll
    for (int d = 0; d < CHD; ++d) vals[d] += sp[d];
  }
  float tp = temp[h];
  float vq = invq * tp;
  float mx = -1e30f;
#pragma unroll
  for (int d = 0; d < CHD; ++d) {
    vals[d] *= vq * sk[h * CHD + d];
    mx = fmaxf(mx, vals[d]);
  }
  float sum = 0.f;
#pragma unroll
  for (int d = 0; d < CHD; ++d) { vals[d] = expf(vals[d] - mx); sum += vals[d]; }
  float inv = 1.f / sum;
  float* Arow = Aat + ((size_t)(b * 8 + h) * 48 + c) * 48;
#pragma unroll
  for (int d = 0; d < CHD; ++d) Arow[d] = vals[d] * inv;
}

// M[b][o][h*48+d] = sum_c wproj[o][h*48+c] * A[b][h*48+c][d], bf16 out,
// stored XOR-swizzled (A-operand layout for k_final_mfma).
__global__ __launch_bounds__(256) void k_combine(
    const float* __restrict__ wproj, const float* __restrict__ Aat,
    unsigned short* __restrict__ M)
{
  int idx = blockIdx.x * 256 + threadIdx.x;      // over 8*384*384
  int b = idx / WELEM;
  int r2 = idx - b * WELEM;
  int o = r2 / DIMC;
  int dg = r2 - o * DIMC;
  int h = dg / CHD, d = dg - h * CHD;
  const float* wrow = wproj + (size_t)o * DIMC + h * CHD;
  const float* Acol = Aat + (size_t)b * DIMC * CHD + (size_t)(h * CHD) * CHD + d;
  float s = 0.f;
#pragma unroll
  for (int c = 0; c < CHD; ++c)
    s = fmaf(wrow[c], Acol[c * CHD], s);
  int dd = (dg & ~63) | ((dg & 63) ^ ((o & 7) << 3));
  M[b * WELEM + o * DIMC + dd] = f2bf(s);
}

extern "C" void kernel_launch(void* const* d_in, const int* in_sizes, int n_in,
                              void* d_out, int out_size, void* d_ws, size_t ws_size,
                              hipStream_t stream)
{
  const float* x     = (const float*)d_in[0];
  const float* w0    = (const float*)d_in[1];
  const float* w1    = (const float*)d_in[2];
  const float* w2    = (const float*)d_in[3];
  const float* dw0   = (const float*)d_in[4];
  const float* dw1   = (const float*)d_in[5];
  const float* dw2   = (const float*)d_in[6];
  const float* wproj = (const float*)d_in[7];
  const float* temp  = (const float*)d_in[8];
  float* out = (float*)d_out;

  // ws layout. vT aliases XT (XT dead after conv_mfma).
  char* p = (char*)d_ws;
  unsigned short* Wc     = (unsigned short*)p;  p += (size_t)3 * WELEM * 2;            // 884,736
  unsigned short* XT     = (unsigned short*)p;  p += (size_t)NB * PERT * 2;            // 100.7 MB
  unsigned short* q0k0v0 = (unsigned short*)p;  p += (size_t)NB * 3 * PERT * 2;        // 302 MB
  unsigned short* qkv    = (unsigned short*)p;  p += (size_t)NB * 3 * PERT * 2;        // 302 MB
  float* Spart   = (float*)p;  p += (size_t)512 * 2304 * 4;                            // 4.7 MB
  float* Aat     = (float*)p;  p += (size_t)NB * DIMC * CHD * 4;                       // 590 KB
  float* partial = (float*)p;  p += (size_t)NB * 3 * DIMC * 8 * 4;                     // 295 KB
  unsigned short* Mbf = (unsigned short*)p;                                            // 2.36 MB
  unsigned short* vT = XT;   // alias

  k_convert_w<<<(3 * WELEM + 255) / 256, 256, 0, stream>>>(w0, w1, w2, Wc);
  k_transpose_x<<<dim3(256, 6, NB), 256, 0, stream>>>(x, XT);
  k_conv_mfma<<<dim3(9, 64, NB), 512, 0, stream>>>(Wc, XT, q0k0v0);
  k_dwconv<<<NB * 3 * DIMC * 8, 256, 0, stream>>>(q0k0v0, dw0, dw1, dw2, qkv, partial);
  k_transpose_v<<<dim3(256, 6, NB), 256, 0, stream>>>(qkv, vT);
  k_qk_mfma<<<512, 256, 0, stream>>>(qkv, Spart);
  k_attn_sm<<<NB, 384, 0, stream>>>(Spart, partial, temp, Aat);
  k_combine<<<(NB * WELEM) / 256, 256, 0, stream>>>(wproj, Aat, Mbf);
  k_final_mfma<<<dim3(3, 64, NB), 512, 0, stream>>>(Mbf, vT, out);
  (void)in_sizes; (void)n_in; (void)out_size; (void)ws_size;
}

// Round 7
// 654.929 us; speedup vs baseline: 7.8596x; 1.1086x over previous
//
#include <hip/hip_runtime.h>
#include <math.h>

#define DIMC 384
#define NHEADS 8
#define CHD 48
#define HWN 16384
#define IMW 128
#define PERT ((size_t)DIMC * HWN)   // elements per [384,128,128] tensor
#define WELEM (DIMC * DIMC)         // 147456
#define NB 8

typedef short short8 __attribute__((ext_vector_type(8)));
typedef unsigned short u16x8 __attribute__((ext_vector_type(8)));
typedef float f32x4 __attribute__((ext_vector_type(4)));

__device__ __forceinline__ unsigned short f2bf(float f) {
  unsigned int u = __float_as_uint(f);
  unsigned int r = (u + 0x7fffu + ((u >> 16) & 1u)) >> 16;   // RNE
  return (unsigned short)r;
}
__device__ __forceinline__ float bf2f(unsigned short b) {
  return __uint_as_float(((unsigned int)b) << 16);
}
__device__ __forceinline__ void async16(const void* g, void* l) {
  __builtin_amdgcn_global_load_lds(
      (const __attribute__((address_space(1))) void*)g,
      (__attribute__((address_space(3))) void*)l, 16, 0, 0);
}

// ---------------------------------------------------------------------------
// bf16 MFMA GEMM, 3-deep counted-vmcnt pipeline (T3/T4/T5). Unchanged from R5.
// ---------------------------------------------------------------------------
template <int OUTBF>
__device__ __forceinline__ void mfma_gemm(
    const unsigned short* __restrict__ A,
    const unsigned short* __restrict__ BT,
    void* __restrict__ Y, int obase, int nbase)
{
  __shared__ unsigned short As[3][8192];    // 3 x 16 KB (128 rows x 128B)
  __shared__ unsigned short Bs[3][16384];   // 3 x 32 KB (256 rows x 128B)
  const int tid = threadIdx.x;
  const int lane = tid & 63;
  const int wv = tid >> 6;              // 0..7
  const int wm = (wv >> 2) * 64;
  const int wn = (wv & 3) * 64;

  f32x4 acc[4][4];
#pragma unroll
  for (int i = 0; i < 4; ++i)
#pragma unroll
    for (int j = 0; j < 4; ++j) acc[i][j] = (f32x4){0.f, 0.f, 0.f, 0.f};

  const int srow = tid >> 3;            // 0..63
  const int sks = (tid & 7) * 8;        // shorts within 64-elem chunk
  const unsigned short* asrc = A + (size_t)(obase + srow) * DIMC + sks;
  const unsigned short* bsrc = BT + (size_t)(nbase + srow) * DIMC + sks;

  const int ar = wm + (lane & 15);
  const int br = wn + (lane & 15);
  const int kg = (lane >> 4) << 4;      // byte offset base within 128B chunk
  const int sw = (lane & 7) << 4;       // row-XOR swizzle

#define WAITVM(n) asm volatile("s_waitcnt vmcnt(" #n ")" ::: "memory")
#define SBAR()                                 \
  do {                                         \
    __builtin_amdgcn_sched_barrier(0);         \
    __builtin_amdgcn_s_barrier();              \
    __builtin_amdgcn_sched_barrier(0);         \
  } while (0)

#define STAGE(buf, k0)                                                   \
  do {                                                                   \
    _Pragma("unroll") for (int i = 0; i < 2; ++i)                        \
        async16(asrc + (size_t)(i * 64) * DIMC + (k0),                   \
                &As[buf][(size_t)(tid + i * 512) * 8]);                  \
    _Pragma("unroll") for (int i = 0; i < 4; ++i)                        \
        async16(bsrc + (size_t)(i * 64) * DIMC + (k0),                   \
                &Bs[buf][(size_t)(tid + i * 512) * 8]);                  \
  } while (0)

#define COMPUTE(buf)                                                     \
  do {                                                                   \
    short8 af[2][4], bf[2][4];                                           \
    _Pragma("unroll") for (int kq = 0; kq < 2; ++kq) {                   \
      const int kb = kq * 64 + kg;                                       \
      _Pragma("unroll") for (int mi = 0; mi < 4; ++mi)                   \
          af[kq][mi] = *reinterpret_cast<const short8*>(                 \
              (const char*)&As[buf][0] + (ar + mi * 16) * 128 + (kb ^ sw)); \
      _Pragma("unroll") for (int ni = 0; ni < 4; ++ni)                   \
          bf[kq][ni] = *reinterpret_cast<const short8*>(                 \
              (const char*)&Bs[buf][0] + (br + ni * 16) * 128 + (kb ^ sw)); \
    }                                                                    \
    __builtin_amdgcn_s_setprio(1);                                       \
    _Pragma("unroll") for (int kq = 0; kq < 2; ++kq)                     \
      _Pragma("unroll") for (int mi = 0; mi < 4; ++mi)                   \
        _Pragma("unroll") for (int ni = 0; ni < 4; ++ni)                 \
          acc[mi][ni] = __builtin_amdgcn_mfma_f32_16x16x32_bf16(         \
              af[kq][mi], bf[kq][ni], acc[mi][ni], 0, 0, 0);             \
    __builtin_amdgcn_s_setprio(0);                                       \
  } while (0)

  // prologue: 3 K-tiles in flight (18 loads/thread outstanding)
  STAGE(0, 0);
  STAGE(1, 64);
  STAGE(2, 128);

  WAITVM(12); SBAR(); COMPUTE(0); SBAR(); STAGE(0, 192);
  WAITVM(12); SBAR(); COMPUTE(1); SBAR(); STAGE(1, 256);
  WAITVM(12); SBAR(); COMPUTE(2); SBAR(); STAGE(2, 320);
  WAITVM(12); SBAR(); COMPUTE(0);
  WAITVM(6);  SBAR(); COMPUTE(1);
  WAITVM(0);  SBAR(); COMPUTE(2);

#undef STAGE
#undef COMPUTE
#undef WAITVM
#undef SBAR

  const int orow = obase + wm + ((lane >> 4) << 2);
  const int ocol = nbase + wn + (lane & 15);
#pragma unroll
  for (int mi = 0; mi < 4; ++mi)
#pragma unroll
    for (int ni = 0; ni < 4; ++ni)
#pragma unroll
      for (int r = 0; r < 4; ++r) {
        size_t off = (size_t)(orow + mi * 16 + r) * HWN + ocol + ni * 16;
        if (OUTBF) ((unsigned short*)Y)[off] = f2bf(acc[mi][ni][r]);
        else       ((float*)Y)[off] = acc[mi][ni][r];
      }
}

// q0k0v0[b] = {w0,w1,w2} @ x[b]. grid (9,64,8).
__global__ __launch_bounds__(512) void k_conv_mfma(
    const unsigned short* __restrict__ Wc, const unsigned short* __restrict__ XT,
    unsigned short* __restrict__ Y)
{
  int lin = ((int)blockIdx.z * 64 + blockIdx.y) * 9 + blockIdx.x;  // 0..4607
  int swz = (lin & 7) * 576 + (lin >> 3);
  int g = swz / 9, r = swz - g * 9;      // g = b*64 + nt
  int bb = g >> 6, nt = g & 63;
  int j = r / 3, mt = r - j * 3;
  mfma_gemm<1>(Wc + j * WELEM, XT + (size_t)bb * PERT,
               Y + (size_t)bb * 3 * PERT + (size_t)j * PERT, mt * 128, nt * 256);
}

// out[b] = M[b] @ v[b]. grid (3,64,8).
__global__ __launch_bounds__(512) void k_final_mfma(
    const unsigned short* __restrict__ M, const unsigned short* __restrict__ vT,
    float* __restrict__ out)
{
  int lin = ((int)blockIdx.z * 64 + blockIdx.y) * 3 + blockIdx.x;  // 0..1535
  int swz = (lin & 7) * 192 + (lin >> 3);
  int g = swz / 3, mt = swz - g * 3;
  int bb = g >> 6, nt = g & 63;
  mfma_gemm<0>(M + (size_t)bb * WELEM, vT + (size_t)bb * PERT,
               out + (size_t)bb * PERT, mt * 128, nt * 256);
}

// transpose+convert x[b][c][n] f32 -> XT[b][n][c] bf16, rows XOR-swizzled.
__global__ __launch_bounds__(256) void k_transpose_x(
    const float* __restrict__ x, unsigned short* __restrict__ XT)
{
  __shared__ unsigned short S[64][72];
  int n0 = blockIdx.x * 64, c0 = blockIdx.y * 64;
  const float* xb = x + (size_t)blockIdx.z * PERT;
  unsigned short* XTb = XT + (size_t)blockIdx.z * PERT;
  int t = threadIdx.x;
  int cl = t >> 2, ns = (t & 3) * 16;
  const float* src = &xb[(size_t)(c0 + cl) * HWN + n0 + ns];
#pragma unroll
  for (int i = 0; i < 16; i += 4) {
    float4 v = *reinterpret_cast<const float4*>(&src[i]);
    S[cl][ns + i + 0] = f2bf(v.x);
    S[cl][ns + i + 1] = f2bf(v.y);
    S[cl][ns + i + 2] = f2bf(v.z);
    S[cl][ns + i + 3] = f2bf(v.w);
  }
  __syncthreads();
  int nl = t >> 2, cs = (t & 3) * 16;
  unsigned short tmp[16];
#pragma unroll
  for (int i = 0; i < 16; ++i) tmp[i] = S[cs + i][nl];
  u16x8 p0, p1;
#pragma unroll
  for (int i = 0; i < 8; ++i) { p0[i] = tmp[i]; p1[i] = tmp[8 + i]; }
  char* rowb = (char*)XTb + (size_t)(n0 + nl) * (DIMC * 2);
  int cb = (c0 + cs) * 2;
  int sw = (nl & 7) << 4;
  *reinterpret_cast<u16x8*>(rowb + ((cb) ^ sw)) = p0;
  *reinterpret_cast<u16x8*>(rowb + ((cb + 16) ^ sw)) = p1;
}

// transpose v[b][c][n] bf16 -> vT[b][n][c] bf16, same swizzle.
__global__ __launch_bounds__(256) void k_transpose_v(
    const unsigned short* __restrict__ qkv, unsigned short* __restrict__ vT)
{
  __shared__ unsigned short S[64][72];
  int n0 = blockIdx.x * 64, c0 = blockIdx.y * 64;
  const unsigned short* v = qkv + (size_t)blockIdx.z * 3 * PERT + 2 * PERT;
  unsigned short* vTb = vT + (size_t)blockIdx.z * PERT;
  int t = threadIdx.x;
  int cl = t >> 2, ns = (t & 3) * 16;
  const unsigned short* src = &v[(size_t)(c0 + cl) * HWN + n0 + ns];
  *reinterpret_cast<u16x8*>(&S[cl][ns]) = *reinterpret_cast<const u16x8*>(&src[0]);
  *reinterpret_cast<u16x8*>(&S[cl][ns + 8]) = *reinterpret_cast<const u16x8*>(&src[8]);
  __syncthreads();
  int nl = t >> 2, cs = (t & 3) * 16;
  unsigned short tmp[16];
#pragma unroll
  for (int i = 0; i < 16; ++i) tmp[i] = S[cs + i][nl];
  u16x8 p0, p1;
#pragma unroll
  for (int i = 0; i < 8; ++i) { p0[i] = tmp[i]; p1[i] = tmp[8 + i]; }
  char* rowb = (char*)vTb + (size_t)(n0 + nl) * (DIMC * 2);
  int cb = (c0 + cs) * 2;
  int sw = (nl & 7) << 4;
  *reinterpret_cast<u16x8*>(rowb + ((cb) ^ sw)) = p0;
  *reinterpret_cast<u16x8*>(rowb + ((cb + 16) ^ sw)) = p1;
}

// w -> bf16, stored XOR-swizzled per 64-elem k-chunk (A-operand layout).
__global__ __launch_bounds__(256) void k_convert_w(
    const float* __restrict__ w0, const float* __restrict__ w1,
    const float* __restrict__ w2, unsigned short* __restrict__ Wc)
{
  int idx = blockIdx.x * 256 + threadIdx.x;      // < 3*147456
  int j = idx / WELEM, r = idx - j * WELEM;
  int m = r / DIMC, k = r - m * DIMC;
  const float* s = (j == 0) ? w0 : (j == 1) ? w1 : w2;
  int kd = (k & ~63) | ((k & 63) ^ ((m & 7) << 3));
  Wc[j * WELEM + m * DIMC + kd] = f2bf(s[r]);
}

// depthwise 3x3 SAME, bf16 in/out, 16 px per thread (one full 16-px group
// per row segment; 8 threads per 128-px row). Left/right halo comes from the
// neighbor lane via __shfl (no scalar edge loads). Boundary rows are
// zero-filled branchlessly so shuffles stay wave-convergent. 4 blocks per
// plane; per-block sum-of-squares partial. planes: [b][j][c], 9216 total.
__global__ __launch_bounds__(256) void k_dwconv(
    const unsigned short* __restrict__ Yin, const float* __restrict__ dw0,
    const float* __restrict__ dw1, const float* __restrict__ dw2,
    unsigned short* __restrict__ Zout, float* __restrict__ partial)
{
  __shared__ float red[4];
  int gid = blockIdx.x * 256 + threadIdx.x;    // unit = 16 px
  int plane = gid >> 10;                        // 1024 units per plane
  int rem = gid & 1023;
  int pl = plane % (3 * DIMC);
  int j = pl / DIMC;
  int c = pl - j * DIMC;
  int h = rem >> 3;
  int wg = (rem & 7) << 4;                      // 0,16,...,112
  int lane = threadIdx.x & 63;                  // lane&7 == rem&7
  const float* dw = ((j == 0) ? dw0 : (j == 1) ? dw1 : dw2) + c * 9;
  const unsigned short* src = Yin + (size_t)plane * HWN;

  float acc[16];
#pragma unroll
  for (int i = 0; i < 16; ++i) acc[i] = 0.f;

#pragma unroll
  for (int dy = -1; dy <= 1; ++dy) {
    int hh = h + dy;
    bool valid = (hh >= 0) && (hh < IMW);
    float mf[16];
    if (valid) {
      const unsigned short* row = src + hh * IMW + wg;
      u16x8 a0 = *reinterpret_cast<const u16x8*>(row);
      u16x8 a1 = *reinterpret_cast<const u16x8*>(row + 8);
#pragma unroll
      for (int i = 0; i < 8; ++i) { mf[i] = bf2f(a0[i]); mf[8 + i] = bf2f(a1[i]); }
    } else {
#pragma unroll
      for (int i = 0; i < 16; ++i) mf[i] = 0.f;
    }
    // halo via neighbor lanes (same row: 8 lanes per row)
    float lf = __shfl_up(mf[15], 1);
    float rf = __shfl_down(mf[0], 1);
    if ((lane & 7) == 0) lf = 0.f;
    if ((lane & 7) == 7) rf = 0.f;
    float t0 = dw[(dy + 1) * 3], t1 = dw[(dy + 1) * 3 + 1], t2 = dw[(dy + 1) * 3 + 2];
    acc[0] = fmaf(lf, t0, fmaf(mf[0], t1, fmaf(mf[1], t2, acc[0])));
#pragma unroll
    for (int i = 1; i < 15; ++i)
      acc[i] = fmaf(mf[i - 1], t0, fmaf(mf[i], t1, fmaf(mf[i + 1], t2, acc[i])));
    acc[15] = fmaf(mf[14], t0, fmaf(mf[15], t1, fmaf(rf, t2, acc[15])));
  }

  u16x8 o0, o1;
#pragma unroll
  for (int i = 0; i < 8; ++i) { o0[i] = f2bf(acc[i]); o1[i] = f2bf(acc[8 + i]); }
  unsigned short* dst = Zout + (size_t)plane * HWN + h * IMW + wg;
  *reinterpret_cast<u16x8*>(dst) = o0;
  *reinterpret_cast<u16x8*>(dst + 8) = o1;

  if (j < 2) {
    float s = 0.f;
#pragma unroll
    for (int i = 0; i < 16; ++i) s = fmaf(acc[i], acc[i], s);
#pragma unroll
    for (int off = 32; off > 0; off >>= 1) s += __shfl_down(s, off);
    if ((threadIdx.x & 63) == 0) red[threadIdx.x >> 6] = s;
    __syncthreads();
    if (threadIdx.x == 0)
      partial[blockIdx.x] = red[0] + red[1] + red[2] + red[3];
  }
}

// q@k^T partials: grid 512 = (b, h, slice of 2048 px). 4 waves x 512 px.
__global__ __launch_bounds__(256) void k_qk_mfma(
    const unsigned short* __restrict__ qkv, float* __restrict__ Spart)
{
  __shared__ float Sred[4][2304];
  int blk = blockIdx.x;
  int b = blk >> 6, h = (blk >> 3) & 7, slice = blk & 7;
  int tid = threadIdx.x, lane = tid & 63, w = tid >> 6;
  const unsigned short* qb = qkv + ((size_t)b * 3 * DIMC + h * CHD) * HWN;
  const unsigned short* kb = qb + (size_t)DIMC * HWN;
  const int row = lane & 15;
  const int ko = (lane >> 4) << 3;
  const int n0 = slice * 2048 + w * 512;

  f32x4 acc[3][3];
#pragma unroll
  for (int i = 0; i < 3; ++i)
#pragma unroll
    for (int j = 0; j < 3; ++j) acc[i][j] = (f32x4){0.f, 0.f, 0.f, 0.f};

  for (int ns = n0; ns < n0 + 512; ns += 32) {
    short8 aq[3], bk[3];
#pragma unroll
    for (int mi = 0; mi < 3; ++mi)
      aq[mi] = *reinterpret_cast<const short8*>(&qb[(size_t)(mi * 16 + row) * HWN + ns + ko]);
#pragma unroll
    for (int ni = 0; ni < 3; ++ni)
      bk[ni] = *reinterpret_cast<const short8*>(&kb[(size_t)(ni * 16 + row) * HWN + ns + ko]);
#pragma unroll
    for (int mi = 0; mi < 3; ++mi)
#pragma unroll
      for (int ni = 0; ni < 3; ++ni)
        acc[mi][ni] = __builtin_amdgcn_mfma_f32_16x16x32_bf16(
            aq[mi], bk[ni], acc[mi][ni], 0, 0, 0);
  }
  const int c0 = (lane >> 4) << 2;
#pragma unroll
  for (int mi = 0; mi < 3; ++mi)
#pragma unroll
    for (int ni = 0; ni < 3; ++ni)
#pragma unroll
      for (int r = 0; r < 4; ++r)
        Sred[w][(mi * 16 + c0 + r) * 48 + ni * 16 + row] = acc[mi][ni][r];
  __syncthreads();
  float* dst = Spart + (size_t)blk * 2304;
#pragma unroll
  for (int i = 0; i < 9; ++i) {
    int e = tid + i * 256;
    dst[e] = Sred[0][e] + Sred[1][e] + Sred[2][e] + Sred[3][e];
  }
}

// slice-sum + L2-norm scale + softmax. grid = 8 (per b), 384 thr = row (h,c).
__global__ __launch_bounds__(384) void k_attn_sm(
    const float* __restrict__ Spart, const float* __restrict__ partial,
    const float* __restrict__ temp, float* __restrict__ Aat)
{
  __shared__ float sk[DIMC];
  int b = blockIdx.x, t = threadIdx.x;
  int h = t / CHD, c = t - h * CHD;
  float sq = 0.f, skk = 0.f;
#pragma unroll
  for (int s = 0; s < 4; ++s) {
    sq  += partial[((size_t)b * 1152 + t) * 4 + s];
    skk += partial[((size_t)b * 1152 + DIMC + t) * 4 + s];
  }
  sk[t] = 1.f / fmaxf(sqrtf(skk), 1e-12f);
  float invq = 1.f / fmaxf(sqrtf(sq), 1e-12f);
  __syncthreads();
  float vals[CHD];
#pragma unroll
  for (int d = 0; d < CHD; ++d) vals[d] = 0.f;
  for (int sl = 0; sl < 8; ++sl) {
    const float* sp = Spart + (size_t)(b * 64 + h * 8 + sl) * 2304 + c * 48;
#pragma unroll
    for (int d = 0; d < CHD; ++d) vals[d] += sp[d];
  }
  float tp = temp[h];
  float vq = invq * tp;
  float mx = -1e30f;
#pragma unroll
  for (int d = 0; d < CHD; ++d) {
    vals[d] *= vq * sk[h * CHD + d];
    mx = fmaxf(mx, vals[d]);
  }
  float sum = 0.f;
#pragma unroll
  for (int d = 0; d < CHD; ++d) { vals[d] = expf(vals[d] - mx); sum += vals[d]; }
  float inv = 1.f / sum;
  float* Arow = Aat + ((size_t)(b * 8 + h) * 48 + c) * 48;
#pragma unroll
  for (int d = 0; d < CHD; ++d) Arow[d] = vals[d] * inv;
}

// M[b][o][h*48+d] = sum_c wproj[o][h*48+c] * A[b][h*48+c][d], bf16 out,
// stored XOR-swizzled (A-operand layout for k_final_mfma).
__global__ __launch_bounds__(256) void k_combine(
    const float* __restrict__ wproj, const float* __restrict__ Aat,
    unsigned short* __restrict__ M)
{
  int idx = blockIdx.x * 256 + threadIdx.x;      // over 8*384*384
  int b = idx / WELEM;
  int r2 = idx - b * WELEM;
  int o = r2 / DIMC;
  int dg = r2 - o * DIMC;
  int h = dg / CHD, d = dg - h * CHD;
  const float* wrow = wproj + (size_t)o * DIMC + h * CHD;
  const float* Acol = Aat + (size_t)b * DIMC * CHD + (size_t)(h * CHD) * CHD + d;
  float s = 0.f;
#pragma unroll
  for (int c = 0; c < CHD; ++c)
    s = fmaf(wrow[c], Acol[c * CHD], s);
  int dd = (dg & ~63) | ((dg & 63) ^ ((o & 7) << 3));
  M[b * WELEM + o * DIMC + dd] = f2bf(s);
}

extern "C" void kernel_launch(void* const* d_in, const int* in_sizes, int n_in,
                              void* d_out, int out_size, void* d_ws, size_t ws_size,
                              hipStream_t stream)
{
  const float* x     = (const float*)d_in[0];
  const float* w0    = (const float*)d_in[1];
  const float* w1    = (const float*)d_in[2];
  const float* w2    = (const float*)d_in[3];
  const float* dw0   = (const float*)d_in[4];
  const float* dw1   = (const float*)d_in[5];
  const float* dw2   = (const float*)d_in[6];
  const float* wproj = (const float*)d_in[7];
  const float* temp  = (const float*)d_in[8];
  float* out = (float*)d_out;

  // ws layout. vT aliases XT (XT dead after conv_mfma).
  char* p = (char*)d_ws;
  unsigned short* Wc     = (unsigned short*)p;  p += (size_t)3 * WELEM * 2;            // 884,736
  unsigned short* XT     = (unsigned short*)p;  p += (size_t)NB * PERT * 2;            // 100.7 MB
  unsigned short* q0k0v0 = (unsigned short*)p;  p += (size_t)NB * 3 * PERT * 2;        // 302 MB
  unsigned short* qkv    = (unsigned short*)p;  p += (size_t)NB * 3 * PERT * 2;        // 302 MB
  float* Spart   = (float*)p;  p += (size_t)512 * 2304 * 4;                            // 4.7 MB
  float* Aat     = (float*)p;  p += (size_t)NB * DIMC * CHD * 4;                       // 590 KB
  float* partial = (float*)p;  p += (size_t)NB * 3 * DIMC * 4 * 4;                     // 147 KB
  unsigned short* Mbf = (unsigned short*)p;                                            // 2.36 MB
  unsigned short* vT = XT;   // alias

  k_convert_w<<<(3 * WELEM + 255) / 256, 256, 0, stream>>>(w0, w1, w2, Wc);
  k_transpose_x<<<dim3(256, 6, NB), 256, 0, stream>>>(x, XT);
  k_conv_mfma<<<dim3(9, 64, NB), 512, 0, stream>>>(Wc, XT, q0k0v0);
  k_dwconv<<<NB * 3 * DIMC * 4, 256, 0, stream>>>(q0k0v0, dw0, dw1, dw2, qkv, partial);
  k_transpose_v<<<dim3(256, 6, NB), 256, 0, stream>>>(qkv, vT);
  k_qk_mfma<<<512, 256, 0, stream>>>(qkv, Spart);
  k_attn_sm<<<NB, 384, 0, stream>>>(Spart, partial, temp, Aat);
  k_combine<<<(NB * WELEM) / 256, 256, 0, stream>>>(wproj, Aat, Mbf);
  k_final_mfma<<<dim3(3, 64, NB), 512, 0, stream>>>(Mbf, vT, out);
  (void)in_sizes; (void)n_in; (void)out_size; (void)ws_size;
}

// Round 8
// 651.204 us; speedup vs baseline: 7.9046x; 1.0057x over previous
//
#include <hip/hip_runtime.h>
#include <math.h>

#define DIMC 384
#define NHEADS 8
#define CHD 48
#define HWN 16384
#define IMW 128
#define PERT ((size_t)DIMC * HWN)   // elements per [384,128,128] tensor
#define WELEM (DIMC * DIMC)         // 147456
#define NB 8

typedef short short8 __attribute__((ext_vector_type(8)));
typedef unsigned short u16x8 __attribute__((ext_vector_type(8)));
typedef float f32x4 __attribute__((ext_vector_type(4)));

__device__ __forceinline__ unsigned short f2bf(float f) {
  unsigned int u = __float_as_uint(f);
  unsigned int r = (u + 0x7fffu + ((u >> 16) & 1u)) >> 16;   // RNE
  return (unsigned short)r;
}
__device__ __forceinline__ float bf2f(unsigned short b) {
  return __uint_as_float(((unsigned int)b) << 16);
}
__device__ __forceinline__ void async16(const void* g, void* l) {
  __builtin_amdgcn_global_load_lds(
      (const __attribute__((address_space(1))) void*)g,
      (__attribute__((address_space(3))) void*)l, 16, 0, 0);
}

// ---------------------------------------------------------------------------
// bf16 MFMA GEMM, 3-deep pipeline, ONE barrier per K-step.
// Key invariant: after the barrier at which stage(t) is known landed, every
// wave has also finished COMPUTE(t-1) (program order), so staging tile t+2
// into buf((t-1)%3) immediately after that barrier is WAR-safe. Stage is
// issued at the START of the compute phase -> ~2 compute phases of latency
// cover; vmcnt never drains below 6 in the loop (T4).
// ---------------------------------------------------------------------------
template <int OUTBF>
__device__ __forceinline__ void mfma_gemm(
    const unsigned short* __restrict__ A,
    const unsigned short* __restrict__ BT,
    void* __restrict__ Y, int obase, int nbase)
{
  __shared__ unsigned short As[3][8192];    // 3 x 16 KB (128 rows x 128B)
  __shared__ unsigned short Bs[3][16384];   // 3 x 32 KB (256 rows x 128B)
  const int tid = threadIdx.x;
  const int lane = tid & 63;
  const int wv = tid >> 6;              // 0..7
  const int wm = (wv >> 2) * 64;
  const int wn = (wv & 3) * 64;

  f32x4 acc[4][4];
#pragma unroll
  for (int i = 0; i < 4; ++i)
#pragma unroll
    for (int j = 0; j < 4; ++j) acc[i][j] = (f32x4){0.f, 0.f, 0.f, 0.f};

  const int srow = tid >> 3;            // 0..63
  const int sks = (tid & 7) * 8;        // shorts within 64-elem chunk
  const unsigned short* asrc = A + (size_t)(obase + srow) * DIMC + sks;
  const unsigned short* bsrc = BT + (size_t)(nbase + srow) * DIMC + sks;

  const int ar = wm + (lane & 15);
  const int br = wn + (lane & 15);
  const int kg = (lane >> 4) << 4;      // byte offset base within 128B chunk
  const int sw = (lane & 7) << 4;       // row-XOR swizzle

#define WAITVM(n) asm volatile("s_waitcnt vmcnt(" #n ")" ::: "memory")
#define SBAR()                                 \
  do {                                         \
    __builtin_amdgcn_sched_barrier(0);         \
    __builtin_amdgcn_s_barrier();              \
    __builtin_amdgcn_sched_barrier(0);         \
  } while (0)

#define STAGE(buf, k0)                                                   \
  do {                                                                   \
    _Pragma("unroll") for (int i = 0; i < 2; ++i)                        \
        async16(asrc + (size_t)(i * 64) * DIMC + (k0),                   \
                &As[buf][(size_t)(tid + i * 512) * 8]);                  \
    _Pragma("unroll") for (int i = 0; i < 4; ++i)                        \
        async16(bsrc + (size_t)(i * 64) * DIMC + (k0),                   \
                &Bs[buf][(size_t)(tid + i * 512) * 8]);                  \
  } while (0)

#define COMPUTE(buf)                                                     \
  do {                                                                   \
    short8 af[2][4], bf[2][4];                                           \
    _Pragma("unroll") for (int kq = 0; kq < 2; ++kq) {                   \
      const int kb = kq * 64 + kg;                                       \
      _Pragma("unroll") for (int mi = 0; mi < 4; ++mi)                   \
          af[kq][mi] = *reinterpret_cast<const short8*>(                 \
              (const char*)&As[buf][0] + (ar + mi * 16) * 128 + (kb ^ sw)); \
      _Pragma("unroll") for (int ni = 0; ni < 4; ++ni)                   \
          bf[kq][ni] = *reinterpret_cast<const short8*>(                 \
              (const char*)&Bs[buf][0] + (br + ni * 16) * 128 + (kb ^ sw)); \
    }                                                                    \
    __builtin_amdgcn_s_setprio(1);                                       \
    _Pragma("unroll") for (int kq = 0; kq < 2; ++kq)                     \
      _Pragma("unroll") for (int mi = 0; mi < 4; ++mi)                   \
        _Pragma("unroll") for (int ni = 0; ni < 4; ++ni)                 \
          acc[mi][ni] = __builtin_amdgcn_mfma_f32_16x16x32_bf16(         \
              af[kq][mi], bf[kq][ni], acc[mi][ni], 0, 0, 0);             \
    __builtin_amdgcn_s_setprio(0);                                       \
  } while (0)

  // prologue: 2 K-tiles in flight (12 loads/wave outstanding)
  STAGE(0, 0);
  STAGE(1, 64);

  // one barrier per K-step; stage issued right after the barrier
  WAITVM(6); SBAR(); STAGE(2, 128); COMPUTE(0);   // t=0
  WAITVM(6); SBAR(); STAGE(0, 192); COMPUTE(1);   // t=1 (buf0: computed t-?; all waves past barrier finished t=0? buf0 computed at t=0 -> overwrite guarded by this barrier)
  WAITVM(6); SBAR(); STAGE(1, 256); COMPUTE(2);   // t=2
  WAITVM(6); SBAR(); STAGE(2, 320); COMPUTE(0);   // t=3
  WAITVM(6); SBAR(); COMPUTE(1);                  // t=4
  WAITVM(0); SBAR(); COMPUTE(2);                  // t=5

#undef STAGE
#undef COMPUTE
#undef WAITVM
#undef SBAR

  const int orow = obase + wm + ((lane >> 4) << 2);
  const int ocol = nbase + wn + (lane & 15);
#pragma unroll
  for (int mi = 0; mi < 4; ++mi)
#pragma unroll
    for (int ni = 0; ni < 4; ++ni)
#pragma unroll
      for (int r = 0; r < 4; ++r) {
        size_t off = (size_t)(orow + mi * 16 + r) * HWN + ocol + ni * 16;
        if (OUTBF) ((unsigned short*)Y)[off] = f2bf(acc[mi][ni][r]);
        else       ((float*)Y)[off] = acc[mi][ni][r];
      }
}

// q0k0v0[b] = {w0,w1,w2} @ x[b]. grid (9,64,8).
__global__ __launch_bounds__(512) void k_conv_mfma(
    const unsigned short* __restrict__ Wc, const unsigned short* __restrict__ XT,
    unsigned short* __restrict__ Y)
{
  int lin = ((int)blockIdx.z * 64 + blockIdx.y) * 9 + blockIdx.x;  // 0..4607
  int swz = (lin & 7) * 576 + (lin >> 3);
  int g = swz / 9, r = swz - g * 9;      // g = b*64 + nt
  int bb = g >> 6, nt = g & 63;
  int j = r / 3, mt = r - j * 3;
  mfma_gemm<1>(Wc + j * WELEM, XT + (size_t)bb * PERT,
               Y + (size_t)bb * 3 * PERT + (size_t)j * PERT, mt * 128, nt * 256);
}

// out[b] = M[b] @ v[b]. grid (3,64,8).
__global__ __launch_bounds__(512) void k_final_mfma(
    const unsigned short* __restrict__ M, const unsigned short* __restrict__ vT,
    float* __restrict__ out)
{
  int lin = ((int)blockIdx.z * 64 + blockIdx.y) * 3 + blockIdx.x;  // 0..1535
  int swz = (lin & 7) * 192 + (lin >> 3);
  int g = swz / 3, mt = swz - g * 3;
  int bb = g >> 6, nt = g & 63;
  mfma_gemm<0>(M + (size_t)bb * WELEM, vT + (size_t)bb * PERT,
               out + (size_t)bb * PERT, mt * 128, nt * 256);
}

// transpose+convert x[b][c][n] f32 -> XT[b][n][c] bf16, rows XOR-swizzled.
__global__ __launch_bounds__(256) void k_transpose_x(
    const float* __restrict__ x, unsigned short* __restrict__ XT)
{
  __shared__ unsigned short S[64][72];
  int n0 = blockIdx.x * 64, c0 = blockIdx.y * 64;
  const float* xb = x + (size_t)blockIdx.z * PERT;
  unsigned short* XTb = XT + (size_t)blockIdx.z * PERT;
  int t = threadIdx.x;
  int cl = t >> 2, ns = (t & 3) * 16;
  const float* src = &xb[(size_t)(c0 + cl) * HWN + n0 + ns];
#pragma unroll
  for (int i = 0; i < 16; i += 4) {
    float4 v = *reinterpret_cast<const float4*>(&src[i]);
    S[cl][ns + i + 0] = f2bf(v.x);
    S[cl][ns + i + 1] = f2bf(v.y);
    S[cl][ns + i + 2] = f2bf(v.z);
    S[cl][ns + i + 3] = f2bf(v.w);
  }
  __syncthreads();
  int nl = t >> 2, cs = (t & 3) * 16;
  unsigned short tmp[16];
#pragma unroll
  for (int i = 0; i < 16; ++i) tmp[i] = S[cs + i][nl];
  u16x8 p0, p1;
#pragma unroll
  for (int i = 0; i < 8; ++i) { p0[i] = tmp[i]; p1[i] = tmp[8 + i]; }
  char* rowb = (char*)XTb + (size_t)(n0 + nl) * (DIMC * 2);
  int cb = (c0 + cs) * 2;
  int sw = (nl & 7) << 4;
  *reinterpret_cast<u16x8*>(rowb + ((cb) ^ sw)) = p0;
  *reinterpret_cast<u16x8*>(rowb + ((cb + 16) ^ sw)) = p1;
}

// transpose v[b][c][n] bf16 -> vT[b][n][c] bf16, same swizzle.
__global__ __launch_bounds__(256) void k_transpose_v(
    const unsigned short* __restrict__ qkv, unsigned short* __restrict__ vT)
{
  __shared__ unsigned short S[64][72];
  int n0 = blockIdx.x * 64, c0 = blockIdx.y * 64;
  const unsigned short* v = qkv + (size_t)blockIdx.z * 3 * PERT + 2 * PERT;
  unsigned short* vTb = vT + (size_t)blockIdx.z * PERT;
  int t = threadIdx.x;
  int cl = t >> 2, ns = (t & 3) * 16;
  const unsigned short* src = &v[(size_t)(c0 + cl) * HWN + n0 + ns];
  *reinterpret_cast<u16x8*>(&S[cl][ns]) = *reinterpret_cast<const u16x8*>(&src[0]);
  *reinterpret_cast<u16x8*>(&S[cl][ns + 8]) = *reinterpret_cast<const u16x8*>(&src[8]);
  __syncthreads();
  int nl = t >> 2, cs = (t & 3) * 16;
  unsigned short tmp[16];
#pragma unroll
  for (int i = 0; i < 16; ++i) tmp[i] = S[cs + i][nl];
  u16x8 p0, p1;
#pragma unroll
  for (int i = 0; i < 8; ++i) { p0[i] = tmp[i]; p1[i] = tmp[8 + i]; }
  char* rowb = (char*)vTb + (size_t)(n0 + nl) * (DIMC * 2);
  int cb = (c0 + cs) * 2;
  int sw = (nl & 7) << 4;
  *reinterpret_cast<u16x8*>(rowb + ((cb) ^ sw)) = p0;
  *reinterpret_cast<u16x8*>(rowb + ((cb + 16) ^ sw)) = p1;
}

// w -> bf16, stored XOR-swizzled per 64-elem k-chunk (A-operand layout).
__global__ __launch_bounds__(256) void k_convert_w(
    const float* __restrict__ w0, const float* __restrict__ w1,
    const float* __restrict__ w2, unsigned short* __restrict__ Wc)
{
  int idx = blockIdx.x * 256 + threadIdx.x;      // < 3*147456
  int j = idx / WELEM, r = idx - j * WELEM;
  int m = r / DIMC, k = r - m * DIMC;
  const float* s = (j == 0) ? w0 : (j == 1) ? w1 : w2;
  int kd = (k & ~63) | ((k & 63) ^ ((m & 7) << 3));
  Wc[j * WELEM + m * DIMC + kd] = f2bf(s[r]);
}

// depthwise 3x3 SAME, bf16 in/out, 16 px per thread; halo via __shfl.
// 4 blocks per plane; per-block sum-of-squares partial.
__global__ __launch_bounds__(256) void k_dwconv(
    const unsigned short* __restrict__ Yin, const float* __restrict__ dw0,
    const float* __restrict__ dw1, const float* __restrict__ dw2,
    unsigned short* __restrict__ Zout, float* __restrict__ partial)
{
  __shared__ float red[4];
  int gid = blockIdx.x * 256 + threadIdx.x;    // unit = 16 px
  int plane = gid >> 10;                        // 1024 units per plane
  int rem = gid & 1023;
  int pl = plane % (3 * DIMC);
  int j = pl / DIMC;
  int c = pl - j * DIMC;
  int h = rem >> 3;
  int wg = (rem & 7) << 4;                      // 0,16,...,112
  int lane = threadIdx.x & 63;                  // lane&7 == rem&7
  const float* dw = ((j == 0) ? dw0 : (j == 1) ? dw1 : dw2) + c * 9;
  const unsigned short* src = Yin + (size_t)plane * HWN;

  float acc[16];
#pragma unroll
  for (int i = 0; i < 16; ++i) acc[i] = 0.f;

#pragma unroll
  for (int dy = -1; dy <= 1; ++dy) {
    int hh = h + dy;
    bool valid = (hh >= 0) && (hh < IMW);
    float mf[16];
    if (valid) {
      const unsigned short* row = src + hh * IMW + wg;
      u16x8 a0 = *reinterpret_cast<const u16x8*>(row);
      u16x8 a1 = *reinterpret_cast<const u16x8*>(row + 8);
#pragma unroll
      for (int i = 0; i < 8; ++i) { mf[i] = bf2f(a0[i]); mf[8 + i] = bf2f(a1[i]); }
    } else {
#pragma unroll
      for (int i = 0; i < 16; ++i) mf[i] = 0.f;
    }
    float lf = __shfl_up(mf[15], 1);
    float rf = __shfl_down(mf[0], 1);
    if ((lane & 7) == 0) lf = 0.f;
    if ((lane & 7) == 7) rf = 0.f;
    float t0 = dw[(dy + 1) * 3], t1 = dw[(dy + 1) * 3 + 1], t2 = dw[(dy + 1) * 3 + 2];
    acc[0] = fmaf(lf, t0, fmaf(mf[0], t1, fmaf(mf[1], t2, acc[0])));
#pragma unroll
    for (int i = 1; i < 15; ++i)
      acc[i] = fmaf(mf[i - 1], t0, fmaf(mf[i], t1, fmaf(mf[i + 1], t2, acc[i])));
    acc[15] = fmaf(mf[14], t0, fmaf(mf[15], t1, fmaf(rf, t2, acc[15])));
  }

  u16x8 o0, o1;
#pragma unroll
  for (int i = 0; i < 8; ++i) { o0[i] = f2bf(acc[i]); o1[i] = f2bf(acc[8 + i]); }
  unsigned short* dst = Zout + (size_t)plane * HWN + h * IMW + wg;
  *reinterpret_cast<u16x8*>(dst) = o0;
  *reinterpret_cast<u16x8*>(dst + 8) = o1;

  if (j < 2) {
    float s = 0.f;
#pragma unroll
    for (int i = 0; i < 16; ++i) s = fmaf(acc[i], acc[i], s);
#pragma unroll
    for (int off = 32; off > 0; off >>= 1) s += __shfl_down(s, off);
    if ((threadIdx.x & 63) == 0) red[threadIdx.x >> 6] = s;
    __syncthreads();
    if (threadIdx.x == 0)
      partial[blockIdx.x] = red[0] + red[1] + red[2] + red[3];
  }
}

// q@k^T partials: grid 512 = (b, h, slice of 2048 px). 4 waves x 512 px.
__global__ __launch_bounds__(256) void k_qk_mfma(
    const unsigned short* __restrict__ qkv, float* __restrict__ Spart)
{
  __shared__ float Sred[4][2304];
  int blk = blockIdx.x;
  int b = blk >> 6, h = (blk >> 3) & 7, slice = blk & 7;
  int tid = threadIdx.x, lane = tid & 63, w = tid >> 6;
  const unsigned short* qb = qkv + ((size_t)b * 3 * DIMC + h * CHD) * HWN;
  const unsigned short* kb = qb + (size_t)DIMC * HWN;
  const int row = lane & 15;
  const int ko = (lane >> 4) << 3;
  const int n0 = slice * 2048 + w * 512;

  f32x4 acc[3][3];
#pragma unroll
  for (int i = 0; i < 3; ++i)
#pragma unroll
    for (int j = 0; j < 3; ++j) acc[i][j] = (f32x4){0.f, 0.f, 0.f, 0.f};

  for (int ns = n0; ns < n0 + 512; ns += 32) {
    short8 aq[3], bk[3];
#pragma unroll
    for (int mi = 0; mi < 3; ++mi)
      aq[mi] = *reinterpret_cast<const short8*>(&qb[(size_t)(mi * 16 + row) * HWN + ns + ko]);
#pragma unroll
    for (int ni = 0; ni < 3; ++ni)
      bk[ni] = *reinterpret_cast<const short8*>(&kb[(size_t)(ni * 16 + row) * HWN + ns + ko]);
#pragma unroll
    for (int mi = 0; mi < 3; ++mi)
#pragma unroll
      for (int ni = 0; ni < 3; ++ni)
        acc[mi][ni] = __builtin_amdgcn_mfma_f32_16x16x32_bf16(
            aq[mi], bk[ni], acc[mi][ni], 0, 0, 0);
  }
  const int c0 = (lane >> 4) << 2;
#pragma unroll
  for (int mi = 0; mi < 3; ++mi)
#pragma unroll
    for (int ni = 0; ni < 3; ++ni)
#pragma unroll
      for (int r = 0; r < 4; ++r)
        Sred[w][(mi * 16 + c0 + r) * 48 + ni * 16 + row] = acc[mi][ni][r];
  __syncthreads();
  float* dst = Spart + (size_t)blk * 2304;
#pragma unroll
  for (int i = 0; i < 9; ++i) {
    int e = tid + i * 256;
    dst[e] = Sred[0][e] + Sred[1][e] + Sred[2][e] + Sred[3][e];
  }
}

// slice-sum + L2-norm scale + softmax. grid = 8 (per b), 384 thr = row (h,c).
__global__ __launch_bounds__(384) void k_attn_sm(
    const float* __restrict__ Spart, const float* __restrict__ partial,
    const float* __restrict__ temp, float* __restrict__ Aat)
{
  __shared__ float sk[DIMC];
  int b = blockIdx.x, t = threadIdx.x;
  int h = t / CHD, c = t - h * CHD;
  float sq = 0.f, skk = 0.f;
#pragma unroll
  for (int s = 0; s < 4; ++s) {
    sq  += partial[((size_t)b * 1152 + t) * 4 + s];
    skk += partial[((size_t)b * 1152 + DIMC + t) * 4 + s];
  }
  sk[t] = 1.f / fmaxf(sqrtf(skk), 1e-12f);
  float invq = 1.f / fmaxf(sqrtf(sq), 1e-12f);
  __syncthreads();
  float vals[CHD];
#pragma unroll
  for (int d = 0; d < CHD; ++d) vals[d] = 0.f;
  for (int sl = 0; sl < 8; ++sl) {
    const float* sp = Spart + (size_t)(b * 64 + h * 8 + sl) * 2304 + c * 48;
#pragma unroll
    for (int d = 0; d < CHD; ++d) vals[d] += sp[d];
  }
  float tp = temp[h];
  float vq = invq * tp;
  float mx = -1e30f;
#pragma unroll
  for (int d = 0; d < CHD; ++d) {
    vals[d] *= vq * sk[h * CHD + d];
    mx = fmaxf(mx, vals[d]);
  }
  float sum = 0.f;
#pragma unroll
  for (int d = 0; d < CHD; ++d) { vals[d] = expf(vals[d] - mx); sum += vals[d]; }
  float inv = 1.f / sum;
  float* Arow = Aat + ((size_t)(b * 8 + h) * 48 + c) * 48;
#pragma unroll
  for (int d = 0; d < CHD; ++d) Arow[d] = vals[d] * inv;
}

// M[b][o][h*48+d] = sum_c wproj[o][h*48+c] * A[b][h*48+c][d], bf16 out,
// stored XOR-swizzled (A-operand layout for k_final_mfma).
__global__ __launch_bounds__(256) void k_combine(
    const float* __restrict__ wproj, const float* __restrict__ Aat,
    unsigned short* __restrict__ M)
{
  int idx = blockIdx.x * 256 + threadIdx.x;      // over 8*384*384
  int b = idx / WELEM;
  int r2 = idx - b * WELEM;
  int o = r2 / DIMC;
  int dg = r2 - o * DIMC;
  int h = dg / CHD, d = dg - h * CHD;
  const float* wrow = wproj + (size_t)o * DIMC + h * CHD;
  const float* Acol = Aat + (size_t)b * DIMC * CHD + (size_t)(h * CHD) * CHD + d;
  float s = 0.f;
#pragma unroll
  for (int c = 0; c < CHD; ++c)
    s = fmaf(wrow[c], Acol[c * CHD], s);
  int dd = (dg & ~63) | ((dg & 63) ^ ((o & 7) << 3));
  M[b * WELEM + o * DIMC + dd] = f2bf(s);
}

extern "C" void kernel_launch(void* const* d_in, const int* in_sizes, int n_in,
                              void* d_out, int out_size, void* d_ws, size_t ws_size,
                              hipStream_t stream)
{
  const float* x     = (const float*)d_in[0];
  const float* w0    = (const float*)d_in[1];
  const float* w1    = (const float*)d_in[2];
  const float* w2    = (const float*)d_in[3];
  const float* dw0   = (const float*)d_in[4];
  const float* dw1   = (const float*)d_in[5];
  const float* dw2   = (const float*)d_in[6];
  const float* wproj = (const float*)d_in[7];
  const float* temp  = (const float*)d_in[8];
  float* out = (float*)d_out;

  // ws layout. vT aliases XT (XT dead after conv_mfma).
  char* p = (char*)d_ws;
  unsigned short* Wc     = (unsigned short*)p;  p += (size_t)3 * WELEM * 2;            // 884,736
  unsigned short* XT     = (unsigned short*)p;  p += (size_t)NB * PERT * 2;            // 100.7 MB
  unsigned short* q0k0v0 = (unsigned short*)p;  p += (size_t)NB * 3 * PERT * 2;        // 302 MB
  unsigned short* qkv    = (unsigned short*)p;  p += (size_t)NB * 3 * PERT * 2;        // 302 MB
  float* Spart   = (float*)p;  p += (size_t)512 * 2304 * 4;                            // 4.7 MB
  float* Aat     = (float*)p;  p += (size_t)NB * DIMC * CHD * 4;                       // 590 KB
  float* partial = (float*)p;  p += (size_t)NB * 3 * DIMC * 4 * 4;                     // 147 KB
  unsigned short* Mbf = (unsigned short*)p;                                            // 2.36 MB
  unsigned short* vT = XT;   // alias

  k_convert_w<<<(3 * WELEM + 255) / 256, 256, 0, stream>>>(w0, w1, w2, Wc);
  k_transpose_x<<<dim3(256, 6, NB), 256, 0, stream>>>(x, XT);
  k_conv_mfma<<<dim3(9, 64, NB), 512, 0, stream>>>(Wc, XT, q0k0v0);
  k_dwconv<<<NB * 3 * DIMC * 4, 256, 0, stream>>>(q0k0v0, dw0, dw1, dw2, qkv, partial);
  k_transpose_v<<<dim3(256, 6, NB), 256, 0, stream>>>(qkv, vT);
  k_qk_mfma<<<512, 256, 0, stream>>>(qkv, Spart);
  k_attn_sm<<<NB, 384, 0, stream>>>(Spart, partial, temp, Aat);
  k_combine<<<(NB * WELEM) / 256, 256, 0, stream>>>(wproj, Aat, Mbf);
  k_final_mfma<<<dim3(3, 64, NB), 512, 0, stream>>>(Mbf, vT, out);
  (void)in_sizes; (void)n_in; (void)out_size; (void)ws_size;
}